// Round 9
// baseline (738.454 us; speedup 1.0000x reference)
//
#include <hip/hip_runtime.h>
#include <cstddef>

constexpr int NUM_ENT_C = 10000;
constexpr int SEQ_C     = 10;
constexpr int H_C       = 200;
constexpr int OUT_C     = 100;
constexpr int NG_C      = 2048;
constexpr int NREL_C    = 240;
constexpr int MQ_C      = 8;

typedef __attribute__((ext_vector_type(8))) short          bf16x8;
typedef __attribute__((ext_vector_type(4))) float          f32x4;
typedef __attribute__((ext_vector_type(8))) unsigned short u16x8;

__device__ __forceinline__ unsigned short f2bf(float v) {
    unsigned u = __float_as_uint(v);
    unsigned r = (u + 0x7FFFu + ((u >> 16) & 1u)) >> 16;   // RTN-even
    return (unsigned short)r;
}
__device__ __forceinline__ float bf2f(unsigned short b) {
    return __uint_as_float((unsigned)b << 16);
}
__device__ __forceinline__ void up2(unsigned u, float& lo, float& hi) {
    lo = __uint_as_float(u << 16);
    hi = __uint_as_float(u & 0xFFFF0000u);
}

// ---------------------------------------------------------------------------
// prep: bf16 tables + zero combined degree array
// ---------------------------------------------------------------------------
__global__ void prep_k(const float* __restrict__ ent, unsigned short* __restrict__ entb, size_t e8,
                       const float* __restrict__ wemb, unsigned short* __restrict__ wembb, size_t w8,
                       int* __restrict__ cdeg, int nNodes) {
    size_t total = e8 + w8 + (size_t)nNodes;
    size_t stride = (size_t)gridDim.x * blockDim.x;
    for (size_t t = (size_t)blockIdx.x * blockDim.x + threadIdx.x; t < total; t += stride) {
        if (t < e8) {
            const float* s = ent + t * 8;
            u16x8 o;
            #pragma unroll
            for (int i = 0; i < 8; ++i) o[i] = f2bf(s[i]);
            *reinterpret_cast<u16x8*>(entb + t * 8) = o;
        } else if (t < e8 + w8) {
            size_t tt = t - e8;
            const float* s = wemb + tt * 8;
            u16x8 o;
            #pragma unroll
            for (int i = 0; i < 8; ++i) o[i] = f2bf(s[i]);
            *reinterpret_cast<u16x8*>(wembb + tt * 8) = o;
        } else {
            cdeg[t - e8 - w8] = 0;
        }
    }
}

// ---------------------------------------------------------------------------
// CSR build over COMBINED node space: word nodes [0,Nw), ent nodes [Nw,Nw+N)
// ---------------------------------------------------------------------------
__global__ void hist2_k(const int* __restrict__ wdst, int Ew,
                        const int* __restrict__ edst, int E,
                        int* __restrict__ cdeg, int Nw) {
    int total = Ew + E;
    int stride = gridDim.x * blockDim.x;
    for (int t = blockIdx.x * blockDim.x + threadIdx.x; t < total; t += stride) {
        if (t < Ew) atomicAdd(&cdeg[wdst[t]], 1);
        else        atomicAdd(&cdeg[Nw + edst[t - Ew]], 1);
    }
}

__global__ void scanA_k(const int* __restrict__ v, int* __restrict__ bsum, int n) {
    __shared__ int s[256];
    int t = threadIdx.x;
    int i = blockIdx.x * 256 + t;
    s[t] = (i < n) ? v[i] : 0;
    __syncthreads();
    for (int d = 128; d; d >>= 1) {
        if (t < d) s[t] += s[t + d];
        __syncthreads();
    }
    if (t == 0) bsum[blockIdx.x] = s[0];
}

// nb <= 512 (holds: (80000+255)/256 = 313)
__global__ void scanB_k(int* __restrict__ bsum, int nb) {
    __shared__ int s[512];
    int t = threadIdx.x;
    int v = (t < nb) ? bsum[t] : 0;
    s[t] = v;
    __syncthreads();
    for (int d = 1; d < 512; d <<= 1) {
        int x = (t >= d) ? s[t - d] : 0;
        __syncthreads();
        s[t] += x;
        __syncthreads();
    }
    if (t < nb) bsum[t] = s[t] - v;   // exclusive
}

__global__ void scanC_k(const int* __restrict__ v, const int* __restrict__ bsum,
                        int* __restrict__ offs, int* __restrict__ cur, int n) {
    __shared__ int s[256];
    int t = threadIdx.x;
    int i = blockIdx.x * 256 + t;
    int val = (i < n) ? v[i] : 0;
    s[t] = val;
    __syncthreads();
    for (int d = 1; d < 256; d <<= 1) {
        int x = (t >= d) ? s[t - d] : 0;
        __syncthreads();
        s[t] += x;
        __syncthreads();
    }
    if (i < n) {
        int ex = s[t] - val + bsum[blockIdx.x];
        offs[i] = ex;
        cur[i]  = ex;
    }
}

// fill with pre-resolved payloads into combined bucket arrays
__global__ void fill2_k(const int* __restrict__ wdst, const int* __restrict__ wsrc,
                        const int* __restrict__ word_id, int Ew,
                        const int* __restrict__ edst, const int* __restrict__ esrc,
                        const int* __restrict__ etype, int E,
                        int* __restrict__ ccur, int Nw,
                        int* __restrict__ bktA, int* __restrict__ bktB) {
    int total = Ew + E;
    int stride = gridDim.x * blockDim.x;
    for (int t = blockIdx.x * blockDim.x + threadIdx.x; t < total; t += stride) {
        if (t < Ew) {
            int s = wsrc[t];
            int p = atomicAdd(&ccur[wdst[t]], 1);
            bktA[p] = word_id[s];
            bktB[p] = s;
        } else {
            int e = t - Ew;
            int p = atomicAdd(&ccur[Nw + edst[e]], 1);
            bktA[p] = esrc[e];
            bktB[p] = etype[e];
        }
    }
}

// ---------------------------------------------------------------------------
// Gather-mean (+ rel-subtract) + self-append, bf16 in/out, vectorized (4/lane)
// DUAL (K1==100): lane halves process 2 edges per iteration.
// ---------------------------------------------------------------------------
template<int K1, int K2, int Kp, bool RELSUB, bool SRCMOD, bool SELFMOD, bool DUAL>
__global__ __launch_bounds__(256) void gather_mean_k(
        const unsigned short* __restrict__ feat, const unsigned short* __restrict__ selfT,
        const float* __restrict__ rel,
        const int* __restrict__ bktS, const int* __restrict__ bktT,
        const int* __restrict__ offs, const int* __restrict__ deg,
        unsigned short* __restrict__ dst, int n) {
    int node = blockIdx.x * 4 + (threadIdx.x >> 6);
    int lane = threadIdx.x & 63;
    if (node >= n) return;
    int off = offs[node], dg = deg[node];
    float acc[4] = {0.f, 0.f, 0.f, 0.f};
    unsigned short* drow = dst + (size_t)node * Kp;

    if (DUAL) {
        int half = lane >> 5, lh = lane & 31;
        int d0 = lh * 4;
        bool act = d0 < K1;
        for (int i = 0; i < dg; i += 2) {
            int ii = i + half;
            if (ii < dg && act) {
                int s = bktS[off + ii];
                if (SRCMOD) s = s % NUM_ENT_C;
                uint2 u = *reinterpret_cast<const uint2*>(feat + (size_t)s * K1 + d0);
                float e0, e1, e2, e3;
                up2(u.x, e0, e1); up2(u.y, e2, e3);
                if (RELSUB) {
                    int tt = bktT[off + ii];
                    float4 rv = *reinterpret_cast<const float4*>(rel + (size_t)tt * K1 + d0);
                    e0 -= rv.x; e1 -= rv.y; e2 -= rv.z; e3 -= rv.w;
                }
                acc[0] += e0; acc[1] += e1; acc[2] += e2; acc[3] += e3;
            }
        }
        #pragma unroll
        for (int c = 0; c < 4; ++c) acc[c] += __shfl_xor(acc[c], 32);
        float inv = 1.f / fmaxf((float)dg, 1.f);
        if (half == 0 && act) {
            uint2 o;
            o.x = (unsigned)f2bf(acc[0] * inv) | ((unsigned)f2bf(acc[1] * inv) << 16);
            o.y = (unsigned)f2bf(acc[2] * inv) | ((unsigned)f2bf(acc[3] * inv) << 16);
            *reinterpret_cast<uint2*>(drow + d0) = o;
        }
        if (K2 > 0 && half == 1 && d0 < K2) {
            int srow = SELFMOD ? (node % NUM_ENT_C) : node;
            uint2 sv = *reinterpret_cast<const uint2*>(selfT + (size_t)srow * K2 + d0);
            *reinterpret_cast<uint2*>(drow + K1 + d0) = sv;
        }
    } else {
        int d0 = lane * 4;
        bool act = d0 < K1;
        for (int i = 0; i < dg; ++i) {
            if (act) {
                int s = bktS[off + i];
                if (SRCMOD) s = s % NUM_ENT_C;
                uint2 u = *reinterpret_cast<const uint2*>(feat + (size_t)s * K1 + d0);
                float e0, e1, e2, e3;
                up2(u.x, e0, e1); up2(u.y, e2, e3);
                if (RELSUB) {
                    int tt = bktT[off + i];
                    float4 rv = *reinterpret_cast<const float4*>(rel + (size_t)tt * K1 + d0);
                    e0 -= rv.x; e1 -= rv.y; e2 -= rv.z; e3 -= rv.w;
                }
                acc[0] += e0; acc[1] += e1; acc[2] += e2; acc[3] += e3;
            }
        }
        float inv = 1.f / fmaxf((float)dg, 1.f);
        if (act) {
            uint2 o;
            o.x = (unsigned)f2bf(acc[0] * inv) | ((unsigned)f2bf(acc[1] * inv) << 16);
            o.y = (unsigned)f2bf(acc[2] * inv) | ((unsigned)f2bf(acc[3] * inv) << 16);
            *reinterpret_cast<uint2*>(drow + d0) = o;
        }
        if (K2 > 0 && d0 < K2) {
            int srow = SELFMOD ? (node % NUM_ENT_C) : node;
            uint2 sv = *reinterpret_cast<const uint2*>(selfT + (size_t)srow * K2 + d0);
            *reinterpret_cast<uint2*>(drow + K1 + d0) = sv;
        }
    }
    for (int cc = K1 + K2 + lane; cc < Kp; cc += 64) drow[cc] = 0;
}

// ---------------------------------------------------------------------------
// All weight blocks -> one bf16 buffer (Wt layout [n][k], zero-padded)
// wc is REORDERED for the fused phase-A kernel: rows [Q(200)|0(24)|ctx(200)|0(24)]
// ---------------------------------------------------------------------------
__global__ void convw_all_k(const float* __restrict__ gcn_w1, const float* __restrict__ gcn_w2,
                            const float* __restrict__ cg1_wn, const float* __restrict__ cg1_wl,
                            const float* __restrict__ cg2_wn, const float* __restrict__ cg2_wl,
                            const float* __restrict__ attn_wa, const float* __restrict__ attn_wc,
                            unsigned short* __restrict__ Wt) {
    constexpr int S0 = 26624;            // gcn_w1  208x128 (K=100,N=200)
    constexpr int S1 = S0 + 46592;       // gcn_w2  208x224 (K=200,N=200)
    constexpr int S2 = S1 + 46592;       // cg1     112x416 (K=400,N=100)
    constexpr int S3 = S2 + 46592;       // cg2     208x224 (K=200,N=200)
    constexpr int S4 = S3 + 46592;       // wa      208x224 (K=200,N=200)
    constexpr int S5 = S4 + 93184;       // wc      208x448 reordered
    int stride = gridDim.x * blockDim.x;
    for (int t = blockIdx.x * blockDim.x + threadIdx.x; t < S5; t += stride) {
        float v = 0.f;
        if (t < S0) {
            int l = t, nn = l >> 7, k = l & 127;
            if (nn < 200 && k < 100) v = gcn_w1[k * 200 + nn];
        } else if (t < S1) {
            int l = t - S0, nn = l / 224, k = l - nn * 224;
            if (nn < 200 && k < 200) v = gcn_w2[k * 200 + nn];
        } else if (t < S2) {
            int l = t - S1, nn = l / 416, k = l - nn * 416;
            if (nn < 100) {
                if (k < 200)      v = cg1_wn[k * 100 + nn];
                else if (k < 400) v = cg1_wl[(k - 200) * 100 + nn];
            }
        } else if (t < S3) {
            int l = t - S2, nn = l / 224, k = l - nn * 224;
            if (nn < 200) {
                if (k < 100)      v = cg2_wn[k * 200 + nn];
                else if (k < 200) v = cg2_wl[(k - 100) * 200 + nn];
            }
        } else if (t < S4) {
            int l = t - S3, nn = l / 224, k = l - nn * 224;
            if (nn < 200 && k < 200) v = attn_wa[k * 200 + nn];
        } else {
            int l = t - S4, nn = l / 448, k = l - nn * 448;
            if (nn < 200) {
                if (k < 200)                  v = attn_wc[(200 + k) * 200 + nn];   // Q part
                else if (k >= 224 && k < 424) v = attn_wc[(k - 224) * 200 + nn];   // ctx part
            }
        }
        Wt[t] = f2bf(v);
    }
}

// ---------------------------------------------------------------------------
// post: build Q rows N..M (bf16), zero pad cols [400,448), rowOff map
// ---------------------------------------------------------------------------
__global__ void post_k(const float* __restrict__ rel2, const int* __restrict__ edge_type,
                       const int* __restrict__ r_ids, unsigned short* __restrict__ A,
                       const int* __restrict__ node_slot, const int* __restrict__ edge_slot,
                       int* __restrict__ rowOff, int N, int M, int divq, int per, int embBase) {
    int R = M - N;
    size_t secA = (size_t)R * H_C;
    size_t secB = secA + (size_t)M * 6;
    size_t total = secB + (size_t)M;
    size_t stride = (size_t)gridDim.x * blockDim.x;
    for (size_t t = (size_t)blockIdx.x * blockDim.x + threadIdx.x; t < total; t += stride) {
        if (t < secA) {
            int r = (int)(t / H_C);
            int d = (int)(t - (size_t)r * H_C);
            int rr = r_ids[r];
            A[(size_t)(N + r) * 448 + 200 + d] = f2bf(rel2[(size_t)edge_type[rr] * H_C + d]);
        } else if (t < secB) {
            size_t l = t - secA;
            int m = (int)(l / 6), c = (int)(l - (size_t)m * 6);
            *reinterpret_cast<uint4*>(A + (size_t)m * 448 + 400 + c * 8) = make_uint4(0u, 0u, 0u, 0u);
        } else {
            int m = (int)(t - secB);
            int offv;
            if (m < N) {
                int ns = node_slot[m];
                offv = embBase + ((ns % NUM_ENT_C) * SEQ_C + ns / divq) * H_C;
            } else {
                int es = edge_slot[m - N];
                offv = ((es / per) * SEQ_C + (es - (es / per) * per)) * H_C;
            }
            rowOff[m] = offv;
        }
    }
}

// ---------------------------------------------------------------------------
// MFMA bf16 GEMM, 64-row blocks
// ---------------------------------------------------------------------------
template<int NF, int ACT, bool SCATTER, bool OBF16>
__global__ __launch_bounds__(256) void mfma_gemm_k(
        const unsigned short* __restrict__ A, int lda,
        const unsigned short* __restrict__ Wt,
        const float* __restrict__ bias, void* __restrict__ Cv, int ldc,
        const int* __restrict__ rowOff, int M, int N, int Kp) {
    constexpr int BN = NF * 16;
    __shared__ unsigned short As[64][40];
    __shared__ unsigned short Bs[BN][40];
    const int tid  = threadIdx.x;
    const int bm   = blockIdx.x * 64;
    const int w    = tid >> 6;
    const int lane = tid & 63;
    const int lr   = lane & 15;
    const int lk   = (lane >> 4) * 8;

    f32x4 acc[NF];
    #pragma unroll
    for (int nf = 0; nf < NF; ++nf) acc[nf] = (f32x4){0.f, 0.f, 0.f, 0.f};

    for (int k0 = 0; k0 < Kp; k0 += 32) {
        {
            int m = tid >> 2, c = tid & 3;
            int gm = bm + m;
            uint4 v = make_uint4(0u, 0u, 0u, 0u);
            if (gm < M) v = *reinterpret_cast<const uint4*>(A + (size_t)gm * lda + k0 + c * 8);
            *reinterpret_cast<uint4*>(&As[m][c * 8]) = v;
        }
        for (int i = tid; i < NF * 64; i += 256) {
            int n = i >> 2, c = i & 3;
            uint4 v = *reinterpret_cast<const uint4*>(Wt + (size_t)n * Kp + k0 + c * 8);
            *reinterpret_cast<uint4*>(&Bs[n][c * 8]) = v;
        }
        __syncthreads();
        bf16x8 a = *reinterpret_cast<const bf16x8*>(&As[w * 16 + lr][lk]);
        #pragma unroll
        for (int nf = 0; nf < NF; ++nf) {
            bf16x8 b = *reinterpret_cast<const bf16x8*>(&Bs[nf * 16 + lr][lk]);
            acc[nf] = __builtin_amdgcn_mfma_f32_16x16x32_bf16(a, b, acc[nf], 0, 0, 0);
        }
        __syncthreads();
    }

    const int r0 = (lane >> 4) * 4;
    #pragma unroll
    for (int j = 0; j < 4; ++j) {
        int gm = bm + w * 16 + r0 + j;
        if (gm >= M) continue;
        size_t base;
        if (SCATTER && !OBF16) base = (size_t)rowOff[gm];
        else                   base = (size_t)gm * ldc;
        #pragma unroll
        for (int nf = 0; nf < NF; ++nf) {
            int gn = nf * 16 + lr;
            if (gn >= N) continue;
            float v = acc[nf][j];
            if (bias) v += bias[gn];
            if (ACT == 1) v = fmaxf(v, 0.f);
            if (ACT == 2) v = tanhf(v);
            if (OBF16) ((unsigned short*)Cv)[base + gn] = f2bf(v);
            else       ((float*)Cv)[base + gn] = v;
        }
    }
}

template<int NF, int ACT, bool SCATTER, bool OBF16>
static void launch_mfma(hipStream_t s, const unsigned short* A, int lda,
                        const unsigned short* Wt, const float* bias,
                        void* C, int ldc, const int* rowOff, int M, int N, int Kp) {
    mfma_gemm_k<NF, ACT, SCATTER, OBF16><<<dim3((M + 63) / 64), 256, 0, s>>>(
        A, lda, Wt, bias, C, ldc, rowOff, M, N, Kp);
}

// ---------------------------------------------------------------------------
// Small f32 GEMM (240-row rel transforms)
// ---------------------------------------------------------------------------
__global__ __launch_bounds__(256) void gemm_f32_k(
        const float* __restrict__ A, const float* __restrict__ W,
        float* __restrict__ C, int M, int N, int K) {
    constexpr int TS = 64, BK = 16;
    __shared__ float As[BK][TS];
    __shared__ float Bs[BK][TS];
    int bm = blockIdx.x * TS, bn = blockIdx.y * TS;
    int tid = threadIdx.x;
    int tx = tid & 15, ty = tid >> 4;
    float acc[4][4] = {};
    for (int k0 = 0; k0 < K; k0 += BK) {
        #pragma unroll
        for (int l = tid; l < TS * BK; l += 256) {
            int m = l >> 4, kk = l & 15;
            int gm = bm + m, gk = k0 + kk;
            As[kk][m] = (gm < M && gk < K) ? A[(size_t)gm * K + gk] : 0.f;
        }
        #pragma unroll
        for (int l = tid; l < TS * BK; l += 256) {
            int kk = l >> 6, n = l & 63;
            int gk = k0 + kk, gn = bn + n;
            Bs[kk][n] = (gk < K && gn < N) ? W[(size_t)gk * N + gn] : 0.f;
        }
        __syncthreads();
        #pragma unroll
        for (int kk = 0; kk < BK; ++kk) {
            float a[4], b[4];
            #pragma unroll
            for (int i = 0; i < 4; ++i) a[i] = As[kk][ty * 4 + i];
            #pragma unroll
            for (int j = 0; j < 4; ++j) b[j] = Bs[kk][tx * 4 + j];
            #pragma unroll
            for (int i = 0; i < 4; ++i)
                #pragma unroll
                for (int j = 0; j < 4; ++j) acc[i][j] += a[i] * b[j];
        }
        __syncthreads();
    }
    #pragma unroll
    for (int i = 0; i < 4; ++i) {
        int gm = bm + ty * 4 + i;
        if (gm >= M) continue;
        #pragma unroll
        for (int j = 0; j < 4; ++j) {
            int gn = bn + tx * 4 + j;
            if (gn < N) C[(size_t)gm * N + gn] = acc[i][j];
        }
    }
}

// ---------------------------------------------------------------------------
// Fused phase A: per 64-row block
//   GEMM1 (Q@wa, K=224) -> QA bf16 in LDS -> per-wave attention (16 rows) ->
//   GEMM2 ([Q(224)||ctx(224)] @ reordered wc, K=448) -> tanh -> scatter f32
// ---------------------------------------------------------------------------
__global__ __launch_bounds__(256) void fusedA_k(
        const unsigned short* __restrict__ AbfQ,   // = AbfF + 200, lda 448
        const unsigned short* __restrict__ WTwa,   // 208 x 224
        const unsigned short* __restrict__ WTwc,   // 208 x 448 reordered
        const unsigned short* __restrict__ whb,
        const int* __restrict__ ent_idx, const int* __restrict__ ent_mask,
        const int* __restrict__ rel_idx, const int* __restrict__ rel_mask,
        const int* __restrict__ rowOff,
        float* __restrict__ outp, int N, int M) {
    constexpr int NF = 13;
    __shared__ unsigned short QL[64][232];   // Q tile  (cols 0..223 valid; stride 232: 464B, 16B-aligned rows)
    __shared__ unsigned short QC[64][232];   // QA then ctx tile
    __shared__ unsigned short Bs[208][40];
    const int tid  = threadIdx.x;
    const int bm   = blockIdx.x * 64;
    const int w    = tid >> 6;
    const int lane = tid & 63;
    const int lr   = lane & 15;
    const int lk   = (lane >> 4) * 8;
    const int r0   = (lane >> 4) * 4;

    // stage Q tile (64 x 224 bf16)
    for (int ch = tid; ch < 64 * 28; ch += 256) {
        int m = ch / 28, c = ch - m * 28;
        int gm = bm + m;
        uint4 v = make_uint4(0u, 0u, 0u, 0u);
        if (gm < M) v = *reinterpret_cast<const uint4*>(AbfQ + (size_t)gm * 448 + c * 8);
        *reinterpret_cast<uint4*>(&QL[m][c * 8]) = v;
    }
    __syncthreads();

    // ---- GEMM1: QA = Q @ wa (K=224, N=200)
    f32x4 acc[NF];
    #pragma unroll
    for (int nf = 0; nf < NF; ++nf) acc[nf] = (f32x4){0.f, 0.f, 0.f, 0.f};
    for (int k0 = 0; k0 < 224; k0 += 32) {
        for (int i = tid; i < NF * 64; i += 256) {
            int n = i >> 2, c = i & 3;
            *reinterpret_cast<uint4*>(&Bs[n][c * 8]) =
                *reinterpret_cast<const uint4*>(WTwa + (size_t)n * 224 + k0 + c * 8);
        }
        __syncthreads();
        bf16x8 a = *reinterpret_cast<const bf16x8*>(&QL[w * 16 + lr][k0 + lk]);
        #pragma unroll
        for (int nf = 0; nf < NF; ++nf) {
            bf16x8 b = *reinterpret_cast<const bf16x8*>(&Bs[nf * 16 + lr][lk]);
            acc[nf] = __builtin_amdgcn_mfma_f32_16x16x32_bf16(a, b, acc[nf], 0, 0, 0);
        }
        __syncthreads();
    }
    // QA -> QC bf16 (wave-local rows; no barrier needed)
    #pragma unroll
    for (int j = 0; j < 4; ++j) {
        #pragma unroll
        for (int nf = 0; nf < NF; ++nf) {
            int gn = nf * 16 + lr;
            if (gn < 200) QC[w * 16 + r0 + j][gn] = f2bf(acc[nf][j]);
        }
    }

    // ---- attention: wave w handles its 16 rows
    {
        int d0 = lane * 4;
        bool act  = d0 < H_C;                 // lanes 0..49
        bool padw = (d0 >= 200 && d0 < 224);  // lanes 50..55 zero the pad cols
        for (int t = 0; t < 16; ++t) {
            int row = w * 16 + t;
            int gm  = bm + row;
            if (gm >= M) continue;            // wave-uniform
            if (padw) *reinterpret_cast<uint2*>(&QC[row][d0]) = make_uint2(0u, 0u);
            const int* idxp;
            const int* mskp;
            if (gm < N) { idxp = ent_idx + (size_t)gm * MQ_C;       mskp = ent_mask + (size_t)gm * MQ_C; }
            else        { idxp = rel_idx + (size_t)(gm - N) * MQ_C; mskp = rel_mask + (size_t)(gm - N) * MQ_C; }
            float qa0 = 0.f, qa1 = 0.f, qa2 = 0.f, qa3 = 0.f;
            if (act) {
                uint2 u = *reinterpret_cast<const uint2*>(&QC[row][d0]);
                up2(u.x, qa0, qa1); up2(u.y, qa2, qa3);
            }
            int  idx[MQ_C];
            int  msk[MQ_C];
            float s[MQ_C];
            uint2 wr[MQ_C];
            #pragma unroll
            for (int k = 0; k < MQ_C; ++k) { idx[k] = idxp[k]; msk[k] = mskp[k]; }
            #pragma unroll
            for (int k = 0; k < MQ_C; ++k) {
                if (msk[k] != 0) {            // wave-uniform mask skip
                    float p = 0.f;
                    if (act) {
                        wr[k] = *reinterpret_cast<const uint2*>(whb + (size_t)idx[k] * H_C + d0);
                        float e0, e1, e2, e3;
                        up2(wr[k].x, e0, e1); up2(wr[k].y, e2, e3);
                        p = qa0 * e0 + qa1 * e1 + qa2 * e2 + qa3 * e3;
                    } else {
                        wr[k] = make_uint2(0u, 0u);
                    }
                    #pragma unroll
                    for (int off = 32; off; off >>= 1) p += __shfl_xor(p, off);
                    s[k] = p;
                } else {
                    s[k] = 0.f;
                    wr[k] = make_uint2(0u, 0u);
                }
            }
            float mx = s[0];
            #pragma unroll
            for (int k = 1; k < MQ_C; ++k) mx = fmaxf(mx, s[k]);
            float den = 0.f;
            #pragma unroll
            for (int k = 0; k < MQ_C; ++k) { s[k] = expf(s[k] - mx); den += s[k]; }
            float inv = 1.f / den;
            if (act) {
                float c0 = 0.f, c1 = 0.f, c2 = 0.f, c3 = 0.f;
                #pragma unroll
                for (int k = 0; k < MQ_C; ++k) {
                    if (msk[k] != 0) {
                        float e0, e1, e2, e3;
                        up2(wr[k].x, e0, e1); up2(wr[k].y, e2, e3);
                        c0 += s[k] * e0; c1 += s[k] * e1; c2 += s[k] * e2; c3 += s[k] * e3;
                    }
                }
                uint2 o;
                o.x = (unsigned)f2bf(c0 * inv) | ((unsigned)f2bf(c1 * inv) << 16);
                o.y = (unsigned)f2bf(c2 * inv) | ((unsigned)f2bf(c3 * inv) << 16);
                *reinterpret_cast<uint2*>(&QC[row][d0]) = o;
            }
        }
    }
    __syncthreads();

    // ---- GEMM2: out = tanh([Q(224) || ctx(224)] @ wc) (K=448, N=200)
    #pragma unroll
    for (int nf = 0; nf < NF; ++nf) acc[nf] = (f32x4){0.f, 0.f, 0.f, 0.f};
    for (int k0i = 0; k0i < 14; ++k0i) {
        for (int i = tid; i < NF * 64; i += 256) {
            int n = i >> 2, c = i & 3;
            *reinterpret_cast<uint4*>(&Bs[n][c * 8]) =
                *reinterpret_cast<const uint4*>(WTwc + (size_t)n * 448 + k0i * 32 + c * 8);
        }
        __syncthreads();
        const unsigned short* Ap = (k0i < 7) ? &QL[0][0] : &QC[0][0];
        int kk = (k0i < 7 ? k0i : k0i - 7) * 32;
        bf16x8 a = *reinterpret_cast<const bf16x8*>(Ap + (size_t)(w * 16 + lr) * 232 + kk + lk);
        #pragma unroll
        for (int nf = 0; nf < NF; ++nf) {
            bf16x8 b = *reinterpret_cast<const bf16x8*>(&Bs[nf * 16 + lr][lk]);
            acc[nf] = __builtin_amdgcn_mfma_f32_16x16x32_bf16(a, b, acc[nf], 0, 0, 0);
        }
        __syncthreads();
    }
    #pragma unroll
    for (int j = 0; j < 4; ++j) {
        int gm = bm + w * 16 + r0 + j;
        if (gm >= M) continue;
        size_t base = (size_t)rowOff[gm];
        #pragma unroll
        for (int nf = 0; nf < NF; ++nf) {
            int gn = nf * 16 + lr;
            if (gn < 200) outp[base + gn] = tanhf(acc[nf][j]);
        }
    }
}

// ---------------------------------------------------------------------------

static inline dim3 ew_grid(size_t total) {
    size_t b = (total + 255) / 256;
    if (b > 4096) b = 4096;
    return dim3((unsigned)b);
}

extern "C" void kernel_launch(void* const* d_in, const int* in_sizes, int n_in,
                              void* d_out, int out_size, void* d_ws, size_t ws_size,
                              hipStream_t stream) {
    const float* ent_embeds = (const float*)d_in[0];
    const float* rel_embeds = (const float*)d_in[1];
    const float* word_embeds= (const float*)d_in[2];
    const float* gcn_w1     = (const float*)d_in[3];
    const float* gcn_b1     = (const float*)d_in[4];
    const float* gcn_w2     = (const float*)d_in[5];
    const float* gcn_b2     = (const float*)d_in[6];
    const float* cg1_wn     = (const float*)d_in[7];
    const float* cg1_wl     = (const float*)d_in[8];
    const float* cg1_wr     = (const float*)d_in[9];
    const float* cg2_wn     = (const float*)d_in[10];
    const float* cg2_wl     = (const float*)d_in[11];
    const float* cg2_wr     = (const float*)d_in[12];
    const float* attn_wa    = (const float*)d_in[13];
    const float* attn_wc    = (const float*)d_in[14];
    const int* node_slot    = (const int*)d_in[15];
    const int* edge_src     = (const int*)d_in[16];
    const int* edge_dst     = (const int*)d_in[17];
    const int* edge_type    = (const int*)d_in[18];
    const int* word_id      = (const int*)d_in[19];
    const int* wsrc         = (const int*)d_in[20];
    const int* wdst         = (const int*)d_in[21];
    const int* ent_word_idx = (const int*)d_in[22];
    const int* ent_word_mask= (const int*)d_in[23];
    const int* rel_word_idx = (const int*)d_in[24];
    const int* rel_word_mask= (const int*)d_in[25];
    const int* r_ids_graph  = (const int*)d_in[26];
    const int* edge_slot    = (const int*)d_in[27];

    const int N    = in_sizes[15];          // 50000
    const int E    = in_sizes[16];          // 200000
    const int Nw   = in_sizes[19];          // 30000
    const int Ew   = in_sizes[20];          // 300000
    const int Rsel = in_sizes[27];          // 8192
    const int M    = N + Rsel;              // 58192
    const int divq = N / SEQ_C;
    const int per  = Rsel / NG_C;
    const int embBase = NG_C * SEQ_C * H_C;
    const size_t entElems  = (size_t)in_sizes[0];   // 2,000,000
    const size_t wembElems = (size_t)in_sizes[2];   // 4,000,000
    const int nNodes = Nw + N;              // 80000 combined CSR node space

    // ---- workspace carving (float-indexed, 16B-aligned sub-buffers)
    float* ws = (float*)d_ws;
    size_t o = 0;
    auto align4 = [&]() { o = (o + 3) & ~(size_t)3; };
    int* cdeg  = (int*)(ws + o); o += nNodes;
    int* coffs = (int*)(ws + o); o += nNodes;
    int* ccur  = (int*)(ws + o); o += nNodes;
    int* bktA  = (int*)(ws + o); o += Ew + E;
    int* bktB  = (int*)(ws + o); o += Ew + E;
    int* bsum  = (int*)(ws + o); o += 512;
    int* rowOff= (int*)(ws + o); o += M;
    float* rel1 = ws + o; o += (size_t)NREL_C * OUT_C;
    float* rel2 = ws + o; o += (size_t)NREL_C * H_C;
    align4();
    unsigned short* Wt      = (unsigned short*)(ws + o); o += 306176 / 2;
    align4();
    unsigned short* wh_bf   = (unsigned short*)(ws + o); o += ((size_t)Nw * H_C) / 2;
    align4();
    unsigned short* h1_bf   = (unsigned short*)(ws + o); o += ((size_t)N * OUT_C) / 2;
    align4();
    unsigned short* ent_bf  = (unsigned short*)(ws + o); o += entElems / 2;
    align4();
    unsigned short* wemb_bf = (unsigned short*)(ws + o); o += wembElems / 2;
    align4();
    unsigned short* AbfF    = (unsigned short*)(ws + o); o += ((size_t)M * 448) / 2;  // [unused||Q||pad]
    align4();
    float* BIG = ws + o;    // phase-local
    unsigned short* wh1_bf = (unsigned short*)BIG;                                  // Nw*200
    unsigned short* AbfW   = (unsigned short*)(BIG + ((size_t)Nw * H_C) / 2);       // Nw*224
    unsigned short* AbfE   = (unsigned short*)BIG;                                  // N*448

    // Wt segment bases (elements)
    unsigned short* WT_g1 = Wt;                 // 208x128
    unsigned short* WT_g2 = Wt + 26624;         // 208x224
    unsigned short* WT_c1 = Wt + 73216;         // 112x416
    unsigned short* WT_c2 = Wt + 119808;        // 208x224
    unsigned short* WT_wa = Wt + 166400;        // 208x224
    unsigned short* WT_wc = Wt + 212992;        // 208x448 (reordered)

    // =============== prep + CSR build + weights ===============
    prep_k<<<ew_grid(entElems / 8 + wembElems / 8 + nNodes), 256, 0, stream>>>(
        ent_embeds, ent_bf, entElems / 8, word_embeds, wemb_bf, wembElems / 8,
        cdeg, nNodes);
    convw_all_k<<<ew_grid(306176), 256, 0, stream>>>(
        gcn_w1, gcn_w2, cg1_wn, cg1_wl, cg2_wn, cg2_wl, attn_wa, attn_wc, Wt);
    hist2_k<<<ew_grid((size_t)Ew + E), 256, 0, stream>>>(wdst, Ew, edge_dst, E, cdeg, Nw);
    {
        int nb = (nNodes + 255) / 256;     // 313 <= 512
        scanA_k<<<nb, 256, 0, stream>>>(cdeg, bsum, nNodes);
        scanB_k<<<1, 512, 0, stream>>>(bsum, nb);
        scanC_k<<<nb, 256, 0, stream>>>(cdeg, bsum, coffs, ccur, nNodes);
    }
    fill2_k<<<ew_grid((size_t)Ew + E), 256, 0, stream>>>(
        wdst, wsrc, word_id, Ew, edge_dst, edge_src, edge_type, E, ccur, Nw, bktA, bktB);
    // rel chains (f32, tiny)
    gemm_f32_k<<<dim3((NREL_C + 63) / 64, (OUT_C + 63) / 64), 256, 0, stream>>>(
        rel_embeds, cg1_wr, rel1, NREL_C, OUT_C, H_C);
    gemm_f32_k<<<dim3((NREL_C + 63) / 64, (H_C + 63) / 64), 256, 0, stream>>>(
        rel1, cg2_wr, rel2, NREL_C, H_C, OUT_C);
    post_k<<<ew_grid((size_t)Rsel * H_C + (size_t)M * 7), 256, 0, stream>>>(
        rel2, edge_type, r_ids_graph, AbfF, node_slot, edge_slot, rowOff,
        N, M, divq, per, embBase);

    // =============== phase W: word GCN ===============
    gather_mean_k<OUT_C, 0, 128, false, false, false, true><<<dim3((Nw + 3) / 4), 256, 0, stream>>>(
        wemb_bf, nullptr, nullptr, bktA, nullptr, coffs, cdeg, AbfW, Nw);
    launch_mfma<13, 1, false, true>(stream, AbfW, 128, WT_g1, gcn_b1, wh1_bf, H_C, nullptr, Nw, H_C, 128);
    gather_mean_k<H_C, 0, 224, false, false, false, false><<<dim3((Nw + 3) / 4), 256, 0, stream>>>(
        wh1_bf, nullptr, nullptr, bktB, nullptr, coffs, cdeg, AbfW, Nw);
    launch_mfma<13, 1, false, true>(stream, AbfW, 224, WT_g2, gcn_b2, wh_bf, H_C, nullptr, Nw, H_C, 224);

    // =============== phase E: CompGCN ===============
    gather_mean_k<H_C, H_C, 448, true, true, true, false><<<dim3((N + 3) / 4), 256, 0, stream>>>(
        ent_bf, ent_bf, rel_embeds, bktA, bktB, coffs + Nw, cdeg + Nw, AbfE, N);
    launch_mfma<7, 1, false, true>(stream, AbfE, 448, WT_c1, nullptr, h1_bf, OUT_C, nullptr, N, OUT_C, 416);
    gather_mean_k<OUT_C, OUT_C, 224, true, false, false, true><<<dim3((N + 3) / 4), 256, 0, stream>>>(
        h1_bf, h1_bf, rel1, bktA, bktB, coffs + Nw, cdeg + Nw, AbfE, N);
    // h2 -> bf16 directly into AbfF cols [200,400), rows [0,N)
    launch_mfma<13, 1, false, true>(stream, AbfE, 224, WT_c2, nullptr, AbfF + 200, 448, nullptr, N, H_C, 224);

    // =============== phase A: fused QA-GEMM + attention + output GEMM ===============
    hipMemsetAsync(d_out, 0, (size_t)out_size * 4, stream);
    fusedA_k<<<dim3((M + 63) / 64), 256, 0, stream>>>(
        AbfF + 200, WT_wa, WT_wc, wh_bf,
        ent_word_idx, ent_word_mask, rel_word_idx, rel_word_mask,
        rowOff, (float*)d_out, N, M);
}

// Round 10
// 673.065 us; speedup vs baseline: 1.0972x; 1.0972x over previous
//
#include <hip/hip_runtime.h>
#include <cstddef>

constexpr int NUM_ENT_C = 10000;
constexpr int SEQ_C     = 10;
constexpr int H_C       = 200;
constexpr int OUT_C     = 100;
constexpr int NG_C      = 2048;
constexpr int NREL_C    = 240;
constexpr int MQ_C      = 8;

typedef __attribute__((ext_vector_type(8))) short          bf16x8;
typedef __attribute__((ext_vector_type(4))) float          f32x4;
typedef __attribute__((ext_vector_type(8))) unsigned short u16x8;

__device__ __forceinline__ unsigned short f2bf(float v) {
    unsigned u = __float_as_uint(v);
    unsigned r = (u + 0x7FFFu + ((u >> 16) & 1u)) >> 16;   // RTN-even
    return (unsigned short)r;
}
__device__ __forceinline__ float bf2f(unsigned short b) {
    return __uint_as_float((unsigned)b << 16);
}
__device__ __forceinline__ void up2(unsigned u, float& lo, float& hi) {
    lo = __uint_as_float(u << 16);
    hi = __uint_as_float(u & 0xFFFF0000u);
}

// ---------------------------------------------------------------------------
// prep: bf16 tables + zero combined degree array
// ---------------------------------------------------------------------------
__global__ void prep_k(const float* __restrict__ ent, unsigned short* __restrict__ entb, size_t e8,
                       const float* __restrict__ wemb, unsigned short* __restrict__ wembb, size_t w8,
                       int* __restrict__ cdeg, int nNodes) {
    size_t total = e8 + w8 + (size_t)nNodes;
    size_t stride = (size_t)gridDim.x * blockDim.x;
    for (size_t t = (size_t)blockIdx.x * blockDim.x + threadIdx.x; t < total; t += stride) {
        if (t < e8) {
            const float* s = ent + t * 8;
            u16x8 o;
            #pragma unroll
            for (int i = 0; i < 8; ++i) o[i] = f2bf(s[i]);
            *reinterpret_cast<u16x8*>(entb + t * 8) = o;
        } else if (t < e8 + w8) {
            size_t tt = t - e8;
            const float* s = wemb + tt * 8;
            u16x8 o;
            #pragma unroll
            for (int i = 0; i < 8; ++i) o[i] = f2bf(s[i]);
            *reinterpret_cast<u16x8*>(wembb + tt * 8) = o;
        } else {
            cdeg[t - e8 - w8] = 0;
        }
    }
}

// ---------------------------------------------------------------------------
// CSR build over COMBINED node space: word nodes [0,Nw), ent nodes [Nw,Nw+N)
// ---------------------------------------------------------------------------
__global__ void hist2_k(const int* __restrict__ wdst, int Ew,
                        const int* __restrict__ edst, int E,
                        int* __restrict__ cdeg, int Nw) {
    int total = Ew + E;
    int stride = gridDim.x * blockDim.x;
    for (int t = blockIdx.x * blockDim.x + threadIdx.x; t < total; t += stride) {
        if (t < Ew) atomicAdd(&cdeg[wdst[t]], 1);
        else        atomicAdd(&cdeg[Nw + edst[t - Ew]], 1);
    }
}

__global__ void scanA_k(const int* __restrict__ v, int* __restrict__ bsum, int n) {
    __shared__ int s[256];
    int t = threadIdx.x;
    int i = blockIdx.x * 256 + t;
    s[t] = (i < n) ? v[i] : 0;
    __syncthreads();
    for (int d = 128; d; d >>= 1) {
        if (t < d) s[t] += s[t + d];
        __syncthreads();
    }
    if (t == 0) bsum[blockIdx.x] = s[0];
}

// nb <= 512 (holds: (80000+255)/256 = 313)
__global__ void scanB_k(int* __restrict__ bsum, int nb) {
    __shared__ int s[512];
    int t = threadIdx.x;
    int v = (t < nb) ? bsum[t] : 0;
    s[t] = v;
    __syncthreads();
    for (int d = 1; d < 512; d <<= 1) {
        int x = (t >= d) ? s[t - d] : 0;
        __syncthreads();
        s[t] += x;
        __syncthreads();
    }
    if (t < nb) bsum[t] = s[t] - v;   // exclusive
}

__global__ void scanC_k(const int* __restrict__ v, const int* __restrict__ bsum,
                        int* __restrict__ offs, int* __restrict__ cur, int n) {
    __shared__ int s[256];
    int t = threadIdx.x;
    int i = blockIdx.x * 256 + t;
    int val = (i < n) ? v[i] : 0;
    s[t] = val;
    __syncthreads();
    for (int d = 1; d < 256; d <<= 1) {
        int x = (t >= d) ? s[t - d] : 0;
        __syncthreads();
        s[t] += x;
        __syncthreads();
    }
    if (i < n) {
        int ex = s[t] - val + bsum[blockIdx.x];
        offs[i] = ex;
        cur[i]  = ex;
    }
}

// fill with pre-resolved payloads into combined bucket arrays
__global__ void fill2_k(const int* __restrict__ wdst, const int* __restrict__ wsrc,
                        const int* __restrict__ word_id, int Ew,
                        const int* __restrict__ edst, const int* __restrict__ esrc,
                        const int* __restrict__ etype, int E,
                        int* __restrict__ ccur, int Nw,
                        int* __restrict__ bktA, int* __restrict__ bktB) {
    int total = Ew + E;
    int stride = gridDim.x * blockDim.x;
    for (int t = blockIdx.x * blockDim.x + threadIdx.x; t < total; t += stride) {
        if (t < Ew) {
            int s = wsrc[t];
            int p = atomicAdd(&ccur[wdst[t]], 1);
            bktA[p] = word_id[s];
            bktB[p] = s;
        } else {
            int e = t - Ew;
            int p = atomicAdd(&ccur[Nw + edst[e]], 1);
            bktA[p] = esrc[e];
            bktB[p] = etype[e];
        }
    }
}

// ---------------------------------------------------------------------------
// Gather-mean (+ rel-subtract) + self-append, bf16 in/out, vectorized (4/lane)
// DUAL (K1==100): lane halves process 2 edges per iteration.
// ---------------------------------------------------------------------------
template<int K1, int K2, int Kp, bool RELSUB, bool SRCMOD, bool SELFMOD, bool DUAL>
__global__ __launch_bounds__(256) void gather_mean_k(
        const unsigned short* __restrict__ feat, const unsigned short* __restrict__ selfT,
        const float* __restrict__ rel,
        const int* __restrict__ bktS, const int* __restrict__ bktT,
        const int* __restrict__ offs, const int* __restrict__ deg,
        unsigned short* __restrict__ dst, int n) {
    int node = blockIdx.x * 4 + (threadIdx.x >> 6);
    int lane = threadIdx.x & 63;
    if (node >= n) return;
    int off = offs[node], dg = deg[node];
    float acc[4] = {0.f, 0.f, 0.f, 0.f};
    unsigned short* drow = dst + (size_t)node * Kp;

    if (DUAL) {
        int half = lane >> 5, lh = lane & 31;
        int d0 = lh * 4;
        bool act = d0 < K1;
        for (int i = 0; i < dg; i += 2) {
            int ii = i + half;
            if (ii < dg && act) {
                int s = bktS[off + ii];
                if (SRCMOD) s = s % NUM_ENT_C;
                uint2 u = *reinterpret_cast<const uint2*>(feat + (size_t)s * K1 + d0);
                float e0, e1, e2, e3;
                up2(u.x, e0, e1); up2(u.y, e2, e3);
                if (RELSUB) {
                    int tt = bktT[off + ii];
                    float4 rv = *reinterpret_cast<const float4*>(rel + (size_t)tt * K1 + d0);
                    e0 -= rv.x; e1 -= rv.y; e2 -= rv.z; e3 -= rv.w;
                }
                acc[0] += e0; acc[1] += e1; acc[2] += e2; acc[3] += e3;
            }
        }
        #pragma unroll
        for (int c = 0; c < 4; ++c) acc[c] += __shfl_xor(acc[c], 32);
        float inv = 1.f / fmaxf((float)dg, 1.f);
        if (half == 0 && act) {
            uint2 o;
            o.x = (unsigned)f2bf(acc[0] * inv) | ((unsigned)f2bf(acc[1] * inv) << 16);
            o.y = (unsigned)f2bf(acc[2] * inv) | ((unsigned)f2bf(acc[3] * inv) << 16);
            *reinterpret_cast<uint2*>(drow + d0) = o;
        }
        if (K2 > 0 && half == 1 && d0 < K2) {
            int srow = SELFMOD ? (node % NUM_ENT_C) : node;
            uint2 sv = *reinterpret_cast<const uint2*>(selfT + (size_t)srow * K2 + d0);
            *reinterpret_cast<uint2*>(drow + K1 + d0) = sv;
        }
    } else {
        int d0 = lane * 4;
        bool act = d0 < K1;
        for (int i = 0; i < dg; ++i) {
            if (act) {
                int s = bktS[off + i];
                if (SRCMOD) s = s % NUM_ENT_C;
                uint2 u = *reinterpret_cast<const uint2*>(feat + (size_t)s * K1 + d0);
                float e0, e1, e2, e3;
                up2(u.x, e0, e1); up2(u.y, e2, e3);
                if (RELSUB) {
                    int tt = bktT[off + i];
                    float4 rv = *reinterpret_cast<const float4*>(rel + (size_t)tt * K1 + d0);
                    e0 -= rv.x; e1 -= rv.y; e2 -= rv.z; e3 -= rv.w;
                }
                acc[0] += e0; acc[1] += e1; acc[2] += e2; acc[3] += e3;
            }
        }
        float inv = 1.f / fmaxf((float)dg, 1.f);
        if (act) {
            uint2 o;
            o.x = (unsigned)f2bf(acc[0] * inv) | ((unsigned)f2bf(acc[1] * inv) << 16);
            o.y = (unsigned)f2bf(acc[2] * inv) | ((unsigned)f2bf(acc[3] * inv) << 16);
            *reinterpret_cast<uint2*>(drow + d0) = o;
        }
        if (K2 > 0 && d0 < K2) {
            int srow = SELFMOD ? (node % NUM_ENT_C) : node;
            uint2 sv = *reinterpret_cast<const uint2*>(selfT + (size_t)srow * K2 + d0);
            *reinterpret_cast<uint2*>(drow + K1 + d0) = sv;
        }
    }
    for (int cc = K1 + K2 + lane; cc < Kp; cc += 64) drow[cc] = 0;
}

// ---------------------------------------------------------------------------
// All weight blocks -> one bf16 buffer (Wt layout [n][k], zero-padded)
// ---------------------------------------------------------------------------
__global__ void convw_all_k(const float* __restrict__ gcn_w1, const float* __restrict__ gcn_w2,
                            const float* __restrict__ cg1_wn, const float* __restrict__ cg1_wl,
                            const float* __restrict__ cg2_wn, const float* __restrict__ cg2_wl,
                            const float* __restrict__ attn_wa, const float* __restrict__ attn_wc,
                            unsigned short* __restrict__ Wt) {
    constexpr int S0 = 26624;            // gcn_w1  208x128 (K=100,N=200)
    constexpr int S1 = S0 + 46592;       // gcn_w2  208x224 (K=200,N=200)
    constexpr int S2 = S1 + 46592;       // cg1     112x416 (K=400,N=100)
    constexpr int S3 = S2 + 46592;       // cg2     208x224 (K=200,N=200)
    constexpr int S4 = S3 + 46592;       // wa      208x224 (K=200,N=200)
    constexpr int S5 = S4 + 86528;       // wc      208x416 (K=400,N=200)
    int stride = gridDim.x * blockDim.x;
    for (int t = blockIdx.x * blockDim.x + threadIdx.x; t < S5; t += stride) {
        float v = 0.f;
        if (t < S0) {
            int l = t, nn = l >> 7, k = l & 127;
            if (nn < 200 && k < 100) v = gcn_w1[k * 200 + nn];
        } else if (t < S1) {
            int l = t - S0, nn = l / 224, k = l - nn * 224;
            if (nn < 200 && k < 200) v = gcn_w2[k * 200 + nn];
        } else if (t < S2) {
            int l = t - S1, nn = l / 416, k = l - nn * 416;
            if (nn < 100) {
                if (k < 200)      v = cg1_wn[k * 100 + nn];
                else if (k < 400) v = cg1_wl[(k - 200) * 100 + nn];
            }
        } else if (t < S3) {
            int l = t - S2, nn = l / 224, k = l - nn * 224;
            if (nn < 200) {
                if (k < 100)      v = cg2_wn[k * 200 + nn];
                else if (k < 200) v = cg2_wl[(k - 100) * 200 + nn];
            }
        } else if (t < S4) {
            int l = t - S3, nn = l / 224, k = l - nn * 224;
            if (nn < 200 && k < 200) v = attn_wa[k * 200 + nn];
        } else {
            int l = t - S4, nn = l / 416, k = l - nn * 416;
            if (nn < 200 && k < 400) v = attn_wc[k * 200 + nn];
        }
        Wt[t] = f2bf(v);
    }
}

// ---------------------------------------------------------------------------
// post: build Q rows N..M (bf16), zero pad cols [400,448), rowOff map
// ---------------------------------------------------------------------------
__global__ void post_k(const float* __restrict__ rel2, const int* __restrict__ edge_type,
                       const int* __restrict__ r_ids, unsigned short* __restrict__ A,
                       const int* __restrict__ node_slot, const int* __restrict__ edge_slot,
                       int* __restrict__ rowOff, int N, int M, int divq, int per, int embBase) {
    int R = M - N;
    size_t secA = (size_t)R * H_C;
    size_t secB = secA + (size_t)M * 6;
    size_t total = secB + (size_t)M;
    size_t stride = (size_t)gridDim.x * blockDim.x;
    for (size_t t = (size_t)blockIdx.x * blockDim.x + threadIdx.x; t < total; t += stride) {
        if (t < secA) {
            int r = (int)(t / H_C);
            int d = (int)(t - (size_t)r * H_C);
            int rr = r_ids[r];
            A[(size_t)(N + r) * 448 + 200 + d] = f2bf(rel2[(size_t)edge_type[rr] * H_C + d]);
        } else if (t < secB) {
            size_t l = t - secA;
            int m = (int)(l / 6), c = (int)(l - (size_t)m * 6);
            *reinterpret_cast<uint4*>(A + (size_t)m * 448 + 400 + c * 8) = make_uint4(0u, 0u, 0u, 0u);
        } else {
            int m = (int)(t - secB);
            int offv;
            if (m < N) {
                int ns = node_slot[m];
                offv = embBase + ((ns % NUM_ENT_C) * SEQ_C + ns / divq) * H_C;
            } else {
                int es = edge_slot[m - N];
                offv = ((es / per) * SEQ_C + (es - (es / per) * per)) * H_C;
            }
            rowOff[m] = offv;
        }
    }
}

// ---------------------------------------------------------------------------
// MFMA bf16 GEMM, 64-row blocks (grid-parallelism over latency hiding):
// 4 waves, wave w owns rows [16w,16w+16) x all N cols (NF fragments).
// ---------------------------------------------------------------------------
template<int NF, int ACT, bool SCATTER, bool OBF16>
__global__ __launch_bounds__(256) void mfma_gemm_k(
        const unsigned short* __restrict__ A, int lda,
        const unsigned short* __restrict__ Wt,
        const float* __restrict__ bias, void* __restrict__ Cv, int ldc,
        const int* __restrict__ rowOff, int M, int N, int Kp) {
    constexpr int BN = NF * 16;
    __shared__ unsigned short As[64][40];
    __shared__ unsigned short Bs[BN][40];
    const int tid  = threadIdx.x;
    const int bm   = blockIdx.x * 64;
    const int w    = tid >> 6;
    const int lane = tid & 63;
    const int lr   = lane & 15;
    const int lk   = (lane >> 4) * 8;

    f32x4 acc[NF];
    #pragma unroll
    for (int nf = 0; nf < NF; ++nf) acc[nf] = (f32x4){0.f, 0.f, 0.f, 0.f};

    for (int k0 = 0; k0 < Kp; k0 += 32) {
        {   // stage A: 64 rows x 32 k = 256 uint4 chunks, 1 per thread
            int m = tid >> 2, c = tid & 3;
            int gm = bm + m;
            uint4 v = make_uint4(0u, 0u, 0u, 0u);
            if (gm < M) v = *reinterpret_cast<const uint4*>(A + (size_t)gm * lda + k0 + c * 8);
            *reinterpret_cast<uint4*>(&As[m][c * 8]) = v;
        }
        for (int i = tid; i < NF * 64; i += 256) {   // stage B
            int n = i >> 2, c = i & 3;
            uint4 v = *reinterpret_cast<const uint4*>(Wt + (size_t)n * Kp + k0 + c * 8);
            *reinterpret_cast<uint4*>(&Bs[n][c * 8]) = v;
        }
        __syncthreads();
        bf16x8 a = *reinterpret_cast<const bf16x8*>(&As[w * 16 + lr][lk]);
        #pragma unroll
        for (int nf = 0; nf < NF; ++nf) {
            bf16x8 b = *reinterpret_cast<const bf16x8*>(&Bs[nf * 16 + lr][lk]);
            acc[nf] = __builtin_amdgcn_mfma_f32_16x16x32_bf16(a, b, acc[nf], 0, 0, 0);
        }
        __syncthreads();
    }

    const int r0 = (lane >> 4) * 4;
    #pragma unroll
    for (int j = 0; j < 4; ++j) {
        int gm = bm + w * 16 + r0 + j;
        if (gm >= M) continue;
        size_t base;
        if (SCATTER && !OBF16) base = (size_t)rowOff[gm];
        else                   base = (size_t)gm * ldc;
        #pragma unroll
        for (int nf = 0; nf < NF; ++nf) {
            int gn = nf * 16 + lr;
            if (gn >= N) continue;
            float v = acc[nf][j];
            if (bias) v += bias[gn];
            if (ACT == 1) v = fmaxf(v, 0.f);
            if (ACT == 2) v = tanhf(v);
            if (OBF16) ((unsigned short*)Cv)[base + gn] = f2bf(v);
            else       ((float*)Cv)[base + gn] = v;
        }
    }
}

template<int NF, int ACT, bool SCATTER, bool OBF16>
static void launch_mfma(hipStream_t s, const unsigned short* A, int lda,
                        const unsigned short* Wt, const float* bias,
                        void* C, int ldc, const int* rowOff, int M, int N, int Kp) {
    mfma_gemm_k<NF, ACT, SCATTER, OBF16><<<dim3((M + 63) / 64), 256, 0, s>>>(
        A, lda, Wt, bias, C, ldc, rowOff, M, N, Kp);
}

// ---------------------------------------------------------------------------
// Small f32 GEMM (240-row rel transforms)
// ---------------------------------------------------------------------------
__global__ __launch_bounds__(256) void gemm_f32_k(
        const float* __restrict__ A, const float* __restrict__ W,
        float* __restrict__ C, int M, int N, int K) {
    constexpr int TS = 64, BK = 16;
    __shared__ float As[BK][TS];
    __shared__ float Bs[BK][TS];
    int bm = blockIdx.x * TS, bn = blockIdx.y * TS;
    int tid = threadIdx.x;
    int tx = tid & 15, ty = tid >> 4;
    float acc[4][4] = {};
    for (int k0 = 0; k0 < K; k0 += BK) {
        #pragma unroll
        for (int l = tid; l < TS * BK; l += 256) {
            int m = l >> 4, kk = l & 15;
            int gm = bm + m, gk = k0 + kk;
            As[kk][m] = (gm < M && gk < K) ? A[(size_t)gm * K + gk] : 0.f;
        }
        #pragma unroll
        for (int l = tid; l < TS * BK; l += 256) {
            int kk = l >> 6, n = l & 63;
            int gk = k0 + kk, gn = bn + n;
            Bs[kk][n] = (gk < K && gn < N) ? W[(size_t)gk * N + gn] : 0.f;
        }
        __syncthreads();
        #pragma unroll
        for (int kk = 0; kk < BK; ++kk) {
            float a[4], b[4];
            #pragma unroll
            for (int i = 0; i < 4; ++i) a[i] = As[kk][ty * 4 + i];
            #pragma unroll
            for (int j = 0; j < 4; ++j) b[j] = Bs[kk][tx * 4 + j];
            #pragma unroll
            for (int i = 0; i < 4; ++i)
                #pragma unroll
                for (int j = 0; j < 4; ++j) acc[i][j] += a[i] * b[j];
        }
        __syncthreads();
    }
    #pragma unroll
    for (int i = 0; i < 4; ++i) {
        int gm = bm + ty * 4 + i;
        if (gm >= M) continue;
        #pragma unroll
        for (int j = 0; j < 4; ++j) {
            int gn = bn + tx * 4 + j;
            if (gn < N) C[(size_t)gm * N + gn] = acc[i][j];
        }
    }
}

// ---------------------------------------------------------------------------
// Attention: one wave/row; bf16 QA + bf16 wh; wave-uniform mask skip
// ---------------------------------------------------------------------------
__global__ __launch_bounds__(256) void attn_k(
        const unsigned short* __restrict__ QAb, const unsigned short* __restrict__ whb,
        const int* __restrict__ ent_idx, const int* __restrict__ ent_mask,
        const int* __restrict__ rel_idx, const int* __restrict__ rel_mask,
        unsigned short* __restrict__ ctxOut, int N, int M) {
    int m = blockIdx.x * 4 + (threadIdx.x >> 6);
    int lane = threadIdx.x & 63;
    if (m >= M) return;
    const int* idxp;
    const int* mskp;
    if (m < N) { idxp = ent_idx + (size_t)m * MQ_C;        mskp = ent_mask + (size_t)m * MQ_C; }
    else       { idxp = rel_idx + (size_t)(m - N) * MQ_C;  mskp = rel_mask + (size_t)(m - N) * MQ_C; }

    int d0 = lane * 4;
    bool act = d0 < H_C;   // lanes 0..49
    float qa0 = 0.f, qa1 = 0.f, qa2 = 0.f, qa3 = 0.f;
    if (act) {
        uint2 u = *reinterpret_cast<const uint2*>(QAb + (size_t)m * H_C + d0);
        up2(u.x, qa0, qa1); up2(u.y, qa2, qa3);
    }
    int  idx[MQ_C];
    int  msk[MQ_C];
    float s[MQ_C];
    uint2 wr[MQ_C];
    #pragma unroll
    for (int k = 0; k < MQ_C; ++k) { idx[k] = idxp[k]; msk[k] = mskp[k]; }
    #pragma unroll
    for (int k = 0; k < MQ_C; ++k) {
        if (msk[k] != 0) {          // wave-uniform branch (one row per wave)
            float p = 0.f;
            if (act) {
                wr[k] = *reinterpret_cast<const uint2*>(whb + (size_t)idx[k] * H_C + d0);
                float e0, e1, e2, e3;
                up2(wr[k].x, e0, e1); up2(wr[k].y, e2, e3);
                p = qa0 * e0 + qa1 * e1 + qa2 * e2 + qa3 * e3;
            } else {
                wr[k] = make_uint2(0u, 0u);
            }
            #pragma unroll
            for (int off = 32; off; off >>= 1) p += __shfl_xor(p, off);
            s[k] = p;
        } else {
            s[k] = 0.f;             // masked score is exactly 0 (matches ref)
            wr[k] = make_uint2(0u, 0u);
        }
    }
    float mx = s[0];
    #pragma unroll
    for (int k = 1; k < MQ_C; ++k) mx = fmaxf(mx, s[k]);
    float den = 0.f;
    #pragma unroll
    for (int k = 0; k < MQ_C; ++k) { s[k] = expf(s[k] - mx); den += s[k]; }
    float inv = 1.f / den;
    if (act) {
        float c0 = 0.f, c1 = 0.f, c2 = 0.f, c3 = 0.f;
        #pragma unroll
        for (int k = 0; k < MQ_C; ++k) {
            if (msk[k] != 0) {      // masked keys contribute 0 to ctx
                float e0, e1, e2, e3;
                up2(wr[k].x, e0, e1); up2(wr[k].y, e2, e3);
                c0 += s[k] * e0; c1 += s[k] * e1; c2 += s[k] * e2; c3 += s[k] * e3;
            }
        }
        uint2 o;
        o.x = (unsigned)f2bf(c0 * inv) | ((unsigned)f2bf(c1 * inv) << 16);
        o.y = (unsigned)f2bf(c2 * inv) | ((unsigned)f2bf(c3 * inv) << 16);
        *reinterpret_cast<uint2*>(ctxOut + (size_t)m * 448 + d0) = o;
    }
}

// ---------------------------------------------------------------------------

static inline dim3 ew_grid(size_t total) {
    size_t b = (total + 255) / 256;
    if (b > 4096) b = 4096;
    return dim3((unsigned)b);
}

extern "C" void kernel_launch(void* const* d_in, const int* in_sizes, int n_in,
                              void* d_out, int out_size, void* d_ws, size_t ws_size,
                              hipStream_t stream) {
    const float* ent_embeds = (const float*)d_in[0];
    const float* rel_embeds = (const float*)d_in[1];
    const float* word_embeds= (const float*)d_in[2];
    const float* gcn_w1     = (const float*)d_in[3];
    const float* gcn_b1     = (const float*)d_in[4];
    const float* gcn_w2     = (const float*)d_in[5];
    const float* gcn_b2     = (const float*)d_in[6];
    const float* cg1_wn     = (const float*)d_in[7];
    const float* cg1_wl     = (const float*)d_in[8];
    const float* cg1_wr     = (const float*)d_in[9];
    const float* cg2_wn     = (const float*)d_in[10];
    const float* cg2_wl     = (const float*)d_in[11];
    const float* cg2_wr     = (const float*)d_in[12];
    const float* attn_wa    = (const float*)d_in[13];
    const float* attn_wc    = (const float*)d_in[14];
    const int* node_slot    = (const int*)d_in[15];
    const int* edge_src     = (const int*)d_in[16];
    const int* edge_dst     = (const int*)d_in[17];
    const int* edge_type    = (const int*)d_in[18];
    const int* word_id      = (const int*)d_in[19];
    const int* wsrc         = (const int*)d_in[20];
    const int* wdst         = (const int*)d_in[21];
    const int* ent_word_idx = (const int*)d_in[22];
    const int* ent_word_mask= (const int*)d_in[23];
    const int* rel_word_idx = (const int*)d_in[24];
    const int* rel_word_mask= (const int*)d_in[25];
    const int* r_ids_graph  = (const int*)d_in[26];
    const int* edge_slot    = (const int*)d_in[27];

    const int N    = in_sizes[15];          // 50000
    const int E    = in_sizes[16];          // 200000
    const int Nw   = in_sizes[19];          // 30000
    const int Ew   = in_sizes[20];          // 300000
    const int Rsel = in_sizes[27];          // 8192
    const int M    = N + Rsel;              // 58192
    const int divq = N / SEQ_C;
    const int per  = Rsel / NG_C;
    const int embBase = NG_C * SEQ_C * H_C;
    const size_t entElems  = (size_t)in_sizes[0];   // 2,000,000
    const size_t wembElems = (size_t)in_sizes[2];   // 4,000,000
    const int nNodes = Nw + N;              // 80000 combined CSR node space

    // ---- workspace carving (float-indexed, 16B-aligned sub-buffers)
    float* ws = (float*)d_ws;
    size_t o = 0;
    auto align4 = [&]() { o = (o + 3) & ~(size_t)3; };
    int* cdeg  = (int*)(ws + o); o += nNodes;
    int* coffs = (int*)(ws + o); o += nNodes;
    int* ccur  = (int*)(ws + o); o += nNodes;
    int* bktA  = (int*)(ws + o); o += Ew + E;
    int* bktB  = (int*)(ws + o); o += Ew + E;
    int* bsum  = (int*)(ws + o); o += 512;
    int* rowOff= (int*)(ws + o); o += M;
    float* rel1 = ws + o; o += (size_t)NREL_C * OUT_C;
    float* rel2 = ws + o; o += (size_t)NREL_C * H_C;
    align4();
    unsigned short* Wt      = (unsigned short*)(ws + o); o += 299520 / 2;
    align4();
    unsigned short* wh_bf   = (unsigned short*)(ws + o); o += ((size_t)Nw * H_C) / 2;
    align4();
    unsigned short* h1_bf   = (unsigned short*)(ws + o); o += ((size_t)N * OUT_C) / 2;
    align4();
    unsigned short* ent_bf  = (unsigned short*)(ws + o); o += entElems / 2;
    align4();
    unsigned short* wemb_bf = (unsigned short*)(ws + o); o += wembElems / 2;
    align4();
    unsigned short* AbfF    = (unsigned short*)(ws + o); o += ((size_t)M * 448) / 2;  // [ctx||Q||pad]
    align4();
    float* BIG = ws + o;    // phase-local
    unsigned short* wh1_bf = (unsigned short*)BIG;                                  // Nw*200
    unsigned short* AbfW   = (unsigned short*)(BIG + ((size_t)Nw * H_C) / 2);       // Nw*224
    unsigned short* AbfE   = (unsigned short*)BIG;                                  // N*448
    unsigned short* QAb    = (unsigned short*)d_out;                                // M*200 bf16

    // Wt segment bases (elements)
    unsigned short* WT_g1 = Wt;                 // 208x128
    unsigned short* WT_g2 = Wt + 26624;         // 208x224
    unsigned short* WT_c1 = Wt + 73216;         // 112x416
    unsigned short* WT_c2 = Wt + 119808;        // 208x224
    unsigned short* WT_wa = Wt + 166400;        // 208x224
    unsigned short* WT_wc = Wt + 212992;        // 208x416

    // =============== prep + CSR build + weights ===============
    prep_k<<<ew_grid(entElems / 8 + wembElems / 8 + nNodes), 256, 0, stream>>>(
        ent_embeds, ent_bf, entElems / 8, word_embeds, wemb_bf, wembElems / 8,
        cdeg, nNodes);
    convw_all_k<<<ew_grid(299520), 256, 0, stream>>>(
        gcn_w1, gcn_w2, cg1_wn, cg1_wl, cg2_wn, cg2_wl, attn_wa, attn_wc, Wt);
    hist2_k<<<ew_grid((size_t)Ew + E), 256, 0, stream>>>(wdst, Ew, edge_dst, E, cdeg, Nw);
    {
        int nb = (nNodes + 255) / 256;     // 313 <= 512
        scanA_k<<<nb, 256, 0, stream>>>(cdeg, bsum, nNodes);
        scanB_k<<<1, 512, 0, stream>>>(bsum, nb);
        scanC_k<<<nb, 256, 0, stream>>>(cdeg, bsum, coffs, ccur, nNodes);
    }
    fill2_k<<<ew_grid((size_t)Ew + E), 256, 0, stream>>>(
        wdst, wsrc, word_id, Ew, edge_dst, edge_src, edge_type, E, ccur, Nw, bktA, bktB);
    // rel chains (f32, tiny)
    gemm_f32_k<<<dim3((NREL_C + 63) / 64, (OUT_C + 63) / 64), 256, 0, stream>>>(
        rel_embeds, cg1_wr, rel1, NREL_C, OUT_C, H_C);
    gemm_f32_k<<<dim3((NREL_C + 63) / 64, (H_C + 63) / 64), 256, 0, stream>>>(
        rel1, cg2_wr, rel2, NREL_C, H_C, OUT_C);
    post_k<<<ew_grid((size_t)Rsel * H_C + (size_t)M * 7), 256, 0, stream>>>(
        rel2, edge_type, r_ids_graph, AbfF, node_slot, edge_slot, rowOff,
        N, M, divq, per, embBase);

    // =============== phase W: word GCN ===============
    // L1: A = mean(wemb_bf[wid]) over wdst   [30000 x 128] (DUAL, K1=100)
    gather_mean_k<OUT_C, 0, 128, false, false, false, true><<<dim3((Nw + 3) / 4), 256, 0, stream>>>(
        wemb_bf, nullptr, nullptr, bktA, nullptr, coffs, cdeg, AbfW, Nw);
    launch_mfma<13, 1, false, true>(stream, AbfW, 128, WT_g1, gcn_b1, wh1_bf, H_C, nullptr, Nw, H_C, 128);
    // L2: A = mean(wh1_bf[wsrc]) over wdst   [30000 x 224]
    gather_mean_k<H_C, 0, 224, false, false, false, false><<<dim3((Nw + 3) / 4), 256, 0, stream>>>(
        wh1_bf, nullptr, nullptr, bktB, nullptr, coffs, cdeg, AbfW, Nw);
    launch_mfma<13, 1, false, true>(stream, AbfW, 224, WT_g2, gcn_b2, wh_bf, H_C, nullptr, Nw, H_C, 224);

    // =============== phase E: CompGCN ===============
    // L1: A = [mean(ent_bf[src%10k] - rel[type]) || ent_bf[n%10k]]   [50000 x 448]
    gather_mean_k<H_C, H_C, 448, true, true, true, false><<<dim3((N + 3) / 4), 256, 0, stream>>>(
        ent_bf, ent_bf, rel_embeds, bktA, bktB, coffs + Nw, cdeg + Nw, AbfE, N);
    launch_mfma<7, 1, false, true>(stream, AbfE, 448, WT_c1, nullptr, h1_bf, OUT_C, nullptr, N, OUT_C, 416);
    // L2: A = [mean(h1_bf[src] - rel1[type]) || h1_bf[n]]   [50000 x 224] (DUAL, K1=100)
    gather_mean_k<OUT_C, OUT_C, 224, true, false, false, true><<<dim3((N + 3) / 4), 256, 0, stream>>>(
        h1_bf, h1_bf, rel1, bktA, bktB, coffs + Nw, cdeg + Nw, AbfE, N);
    // h2 -> bf16 directly into AbfF cols [200,400), rows [0,N)
    launch_mfma<13, 1, false, true>(stream, AbfE, 224, WT_c2, nullptr, AbfF + 200, 448, nullptr, N, H_C, 224);

    // =============== phase A: attention + output ===============
    // QA = Q @ wa  (A = AbfF cols 200..424, lda=448) -> bf16 in d_out
    launch_mfma<13, 0, false, true>(stream, AbfF + 200, 448, WT_wa, nullptr, QAb, H_C, nullptr, M, H_C, 224);
    attn_k<<<(M + 3) / 4, 256, 0, stream>>>(QAb, wh_bf, ent_word_idx, ent_word_mask,
                                            rel_word_idx, rel_word_mask, AbfF, N, M);
    // final: out = tanh([ctx||Q] @ wc) scattered into zeroed d_out
    hipMemsetAsync(d_out, 0, (size_t)out_size * 4, stream);
    launch_mfma<13, 2, true, false>(stream, AbfF, 448, WT_wc, nullptr, d_out, H_C, rowOff, M, H_C, 416);
}

// Round 11
// 670.276 us; speedup vs baseline: 1.1017x; 1.0042x over previous
//
#include <hip/hip_runtime.h>
#include <cstddef>

constexpr int NUM_ENT_C = 10000;
constexpr int SEQ_C     = 10;
constexpr int H_C       = 200;
constexpr int OUT_C     = 100;
constexpr int NG_C      = 2048;
constexpr int NREL_C    = 240;
constexpr int MQ_C      = 8;

typedef __attribute__((ext_vector_type(8))) short          bf16x8;
typedef __attribute__((ext_vector_type(4))) float          f32x4;
typedef __attribute__((ext_vector_type(8))) unsigned short u16x8;

__device__ __forceinline__ unsigned short f2bf(float v) {
    unsigned u = __float_as_uint(v);
    unsigned r = (u + 0x7FFFu + ((u >> 16) & 1u)) >> 16;   // RTN-even
    return (unsigned short)r;
}
__device__ __forceinline__ float bf2f(unsigned short b) {
    return __uint_as_float((unsigned)b << 16);
}
__device__ __forceinline__ void up2(unsigned u, float& lo, float& hi) {
    lo = __uint_as_float(u << 16);
    hi = __uint_as_float(u & 0xFFFF0000u);
}

// ---------------------------------------------------------------------------
// prep: bf16 tables + zero combined degree array
// ---------------------------------------------------------------------------
__global__ void prep_k(const float* __restrict__ ent, unsigned short* __restrict__ entb, size_t e8,
                       const float* __restrict__ wemb, unsigned short* __restrict__ wembb, size_t w8,
                       int* __restrict__ cdeg, int nNodes) {
    size_t total = e8 + w8 + (size_t)nNodes;
    size_t stride = (size_t)gridDim.x * blockDim.x;
    for (size_t t = (size_t)blockIdx.x * blockDim.x + threadIdx.x; t < total; t += stride) {
        if (t < e8) {
            const float* s = ent + t * 8;
            u16x8 o;
            #pragma unroll
            for (int i = 0; i < 8; ++i) o[i] = f2bf(s[i]);
            *reinterpret_cast<u16x8*>(entb + t * 8) = o;
        } else if (t < e8 + w8) {
            size_t tt = t - e8;
            const float* s = wemb + tt * 8;
            u16x8 o;
            #pragma unroll
            for (int i = 0; i < 8; ++i) o[i] = f2bf(s[i]);
            *reinterpret_cast<u16x8*>(wembb + tt * 8) = o;
        } else {
            cdeg[t - e8 - w8] = 0;
        }
    }
}

// ---------------------------------------------------------------------------
// CSR build over COMBINED node space: word nodes [0,Nw), ent nodes [Nw,Nw+N)
// ---------------------------------------------------------------------------
__global__ void hist2_k(const int* __restrict__ wdst, int Ew,
                        const int* __restrict__ edst, int E,
                        int* __restrict__ cdeg, int Nw) {
    int total = Ew + E;
    int stride = gridDim.x * blockDim.x;
    for (int t = blockIdx.x * blockDim.x + threadIdx.x; t < total; t += stride) {
        if (t < Ew) atomicAdd(&cdeg[wdst[t]], 1);
        else        atomicAdd(&cdeg[Nw + edst[t - Ew]], 1);
    }
}

__global__ void scanA_k(const int* __restrict__ v, int* __restrict__ bsum, int n) {
    __shared__ int s[256];
    int t = threadIdx.x;
    int i = blockIdx.x * 256 + t;
    s[t] = (i < n) ? v[i] : 0;
    __syncthreads();
    for (int d = 128; d; d >>= 1) {
        if (t < d) s[t] += s[t + d];
        __syncthreads();
    }
    if (t == 0) bsum[blockIdx.x] = s[0];
}

// nb <= 512 (holds: (80000+255)/256 = 313)
__global__ void scanB_k(int* __restrict__ bsum, int nb) {
    __shared__ int s[512];
    int t = threadIdx.x;
    int v = (t < nb) ? bsum[t] : 0;
    s[t] = v;
    __syncthreads();
    for (int d = 1; d < 512; d <<= 1) {
        int x = (t >= d) ? s[t - d] : 0;
        __syncthreads();
        s[t] += x;
        __syncthreads();
    }
    if (t < nb) bsum[t] = s[t] - v;   // exclusive
}

__global__ void scanC_k(const int* __restrict__ v, const int* __restrict__ bsum,
                        int* __restrict__ offs, int* __restrict__ cur, int n) {
    __shared__ int s[256];
    int t = threadIdx.x;
    int i = blockIdx.x * 256 + t;
    int val = (i < n) ? v[i] : 0;
    s[t] = val;
    __syncthreads();
    for (int d = 1; d < 256; d <<= 1) {
        int x = (t >= d) ? s[t - d] : 0;
        __syncthreads();
        s[t] += x;
        __syncthreads();
    }
    if (i < n) {
        int ex = s[t] - val + bsum[blockIdx.x];
        offs[i] = ex;
        cur[i]  = ex;
    }
}

// fill with pre-resolved payloads into combined bucket arrays
__global__ void fill2_k(const int* __restrict__ wdst, const int* __restrict__ wsrc,
                        const int* __restrict__ word_id, int Ew,
                        const int* __restrict__ edst, const int* __restrict__ esrc,
                        const int* __restrict__ etype, int E,
                        int* __restrict__ ccur, int Nw,
                        int* __restrict__ bktA, int* __restrict__ bktB) {
    int total = Ew + E;
    int stride = gridDim.x * blockDim.x;
    for (int t = blockIdx.x * blockDim.x + threadIdx.x; t < total; t += stride) {
        if (t < Ew) {
            int s = wsrc[t];
            int p = atomicAdd(&ccur[wdst[t]], 1);
            bktA[p] = word_id[s];
            bktB[p] = s;
        } else {
            int e = t - Ew;
            int p = atomicAdd(&ccur[Nw + edst[e]], 1);
            bktA[p] = esrc[e];
            bktB[p] = etype[e];
        }
    }
}

// ---------------------------------------------------------------------------
// Gather-mean (+ rel-subtract) + self-append, bf16 in/out, vectorized (4/lane)
// DUAL (K1==100): lane halves process 2 edges per iteration.
// ---------------------------------------------------------------------------
template<int K1, int K2, int Kp, bool RELSUB, bool SRCMOD, bool SELFMOD, bool DUAL>
__global__ __launch_bounds__(256) void gather_mean_k(
        const unsigned short* __restrict__ feat, const unsigned short* __restrict__ selfT,
        const float* __restrict__ rel,
        const int* __restrict__ bktS, const int* __restrict__ bktT,
        const int* __restrict__ offs, const int* __restrict__ deg,
        unsigned short* __restrict__ dst, int n) {
    int node = blockIdx.x * 4 + (threadIdx.x >> 6);
    int lane = threadIdx.x & 63;
    if (node >= n) return;
    int off = offs[node], dg = deg[node];
    float acc[4] = {0.f, 0.f, 0.f, 0.f};
    unsigned short* drow = dst + (size_t)node * Kp;

    if (DUAL) {
        int half = lane >> 5, lh = lane & 31;
        int d0 = lh * 4;
        bool act = d0 < K1;
        for (int i = 0; i < dg; i += 2) {
            int ii = i + half;
            if (ii < dg && act) {
                int s = bktS[off + ii];
                if (SRCMOD) s = s % NUM_ENT_C;
                uint2 u = *reinterpret_cast<const uint2*>(feat + (size_t)s * K1 + d0);
                float e0, e1, e2, e3;
                up2(u.x, e0, e1); up2(u.y, e2, e3);
                if (RELSUB) {
                    int tt = bktT[off + ii];
                    float4 rv = *reinterpret_cast<const float4*>(rel + (size_t)tt * K1 + d0);
                    e0 -= rv.x; e1 -= rv.y; e2 -= rv.z; e3 -= rv.w;
                }
                acc[0] += e0; acc[1] += e1; acc[2] += e2; acc[3] += e3;
            }
        }
        #pragma unroll
        for (int c = 0; c < 4; ++c) acc[c] += __shfl_xor(acc[c], 32);
        float inv = 1.f / fmaxf((float)dg, 1.f);
        if (half == 0 && act) {
            uint2 o;
            o.x = (unsigned)f2bf(acc[0] * inv) | ((unsigned)f2bf(acc[1] * inv) << 16);
            o.y = (unsigned)f2bf(acc[2] * inv) | ((unsigned)f2bf(acc[3] * inv) << 16);
            *reinterpret_cast<uint2*>(drow + d0) = o;
        }
        if (K2 > 0 && half == 1 && d0 < K2) {
            int srow = SELFMOD ? (node % NUM_ENT_C) : node;
            uint2 sv = *reinterpret_cast<const uint2*>(selfT + (size_t)srow * K2 + d0);
            *reinterpret_cast<uint2*>(drow + K1 + d0) = sv;
        }
    } else {
        int d0 = lane * 4;
        bool act = d0 < K1;
        for (int i = 0; i < dg; ++i) {
            if (act) {
                int s = bktS[off + i];
                if (SRCMOD) s = s % NUM_ENT_C;
                uint2 u = *reinterpret_cast<const uint2*>(feat + (size_t)s * K1 + d0);
                float e0, e1, e2, e3;
                up2(u.x, e0, e1); up2(u.y, e2, e3);
                if (RELSUB) {
                    int tt = bktT[off + i];
                    float4 rv = *reinterpret_cast<const float4*>(rel + (size_t)tt * K1 + d0);
                    e0 -= rv.x; e1 -= rv.y; e2 -= rv.z; e3 -= rv.w;
                }
                acc[0] += e0; acc[1] += e1; acc[2] += e2; acc[3] += e3;
            }
        }
        float inv = 1.f / fmaxf((float)dg, 1.f);
        if (act) {
            uint2 o;
            o.x = (unsigned)f2bf(acc[0] * inv) | ((unsigned)f2bf(acc[1] * inv) << 16);
            o.y = (unsigned)f2bf(acc[2] * inv) | ((unsigned)f2bf(acc[3] * inv) << 16);
            *reinterpret_cast<uint2*>(drow + d0) = o;
        }
        if (K2 > 0 && d0 < K2) {
            int srow = SELFMOD ? (node % NUM_ENT_C) : node;
            uint2 sv = *reinterpret_cast<const uint2*>(selfT + (size_t)srow * K2 + d0);
            *reinterpret_cast<uint2*>(drow + K1 + d0) = sv;
        }
    }
    for (int cc = K1 + K2 + lane; cc < Kp; cc += 64) drow[cc] = 0;
}

// ---------------------------------------------------------------------------
// All weight blocks -> one bf16 buffer (Wt layout [n][k], zero-padded)
// Segments padded to 224 rows so column-split GEMMs can read rows [112,224)
// ---------------------------------------------------------------------------
__global__ void convw_all_k(const float* __restrict__ gcn_w1, const float* __restrict__ gcn_w2,
                            const float* __restrict__ cg1_wn, const float* __restrict__ cg1_wl,
                            const float* __restrict__ cg2_wn, const float* __restrict__ cg2_wl,
                            const float* __restrict__ attn_wa, const float* __restrict__ attn_wc,
                            unsigned short* __restrict__ Wt) {
    constexpr int S0 = 28672;            // gcn_w1  224x128 (K=100,N=200)
    constexpr int S1 = S0 + 50176;       // gcn_w2  224x224 (K=200,N=200)
    constexpr int S2 = S1 + 46592;       // cg1     112x416 (K=400,N=100)
    constexpr int S3 = S2 + 50176;       // cg2     224x224 (K=200,N=200)
    constexpr int S4 = S3 + 50176;       // wa      224x224 (K=200,N=200)
    constexpr int S5 = S4 + 93184;       // wc      224x416 (K=400,N=200)
    int stride = gridDim.x * blockDim.x;
    for (int t = blockIdx.x * blockDim.x + threadIdx.x; t < S5; t += stride) {
        float v = 0.f;
        if (t < S0) {
            int l = t, nn = l >> 7, k = l & 127;
            if (nn < 200 && k < 100) v = gcn_w1[k * 200 + nn];
        } else if (t < S1) {
            int l = t - S0, nn = l / 224, k = l - nn * 224;
            if (nn < 200 && k < 200) v = gcn_w2[k * 200 + nn];
        } else if (t < S2) {
            int l = t - S1, nn = l / 416, k = l - nn * 416;
            if (nn < 100) {
                if (k < 200)      v = cg1_wn[k * 100 + nn];
                else if (k < 400) v = cg1_wl[(k - 200) * 100 + nn];
            }
        } else if (t < S3) {
            int l = t - S2, nn = l / 224, k = l - nn * 224;
            if (nn < 200) {
                if (k < 100)      v = cg2_wn[k * 200 + nn];
                else if (k < 200) v = cg2_wl[(k - 100) * 200 + nn];
            }
        } else if (t < S4) {
            int l = t - S3, nn = l / 224, k = l - nn * 224;
            if (nn < 200 && k < 200) v = attn_wa[k * 200 + nn];
        } else {
            int l = t - S4, nn = l / 416, k = l - nn * 416;
            if (nn < 200 && k < 400) v = attn_wc[k * 200 + nn];
        }
        Wt[t] = f2bf(v);
    }
}

// ---------------------------------------------------------------------------
// post: build Q rows N..M (bf16), zero pad cols [400,448), rowOff map
// ---------------------------------------------------------------------------
__global__ void post_k(const float* __restrict__ rel2, const int* __restrict__ edge_type,
                       const int* __restrict__ r_ids, unsigned short* __restrict__ A,
                       const int* __restrict__ node_slot, const int* __restrict__ edge_slot,
                       int* __restrict__ rowOff, int N, int M, int divq, int per, int embBase) {
    int R = M - N;
    size_t secA = (size_t)R * H_C;
    size_t secB = secA + (size_t)M * 6;
    size_t total = secB + (size_t)M;
    size_t stride = (size_t)gridDim.x * blockDim.x;
    for (size_t t = (size_t)blockIdx.x * blockDim.x + threadIdx.x; t < total; t += stride) {
        if (t < secA) {
            int r = (int)(t / H_C);
            int d = (int)(t - (size_t)r * H_C);
            int rr = r_ids[r];
            A[(size_t)(N + r) * 448 + 200 + d] = f2bf(rel2[(size_t)edge_type[rr] * H_C + d]);
        } else if (t < secB) {
            size_t l = t - secA;
            int m = (int)(l / 6), c = (int)(l - (size_t)m * 6);
            *reinterpret_cast<uint4*>(A + (size_t)m * 448 + 400 + c * 8) = make_uint4(0u, 0u, 0u, 0u);
        } else {
            int m = (int)(t - secB);
            int offv;
            if (m < N) {
                int ns = node_slot[m];
                offv = embBase + ((ns % NUM_ENT_C) * SEQ_C + ns / divq) * H_C;
            } else {
                int es = edge_slot[m - N];
                offv = ((es / per) * SEQ_C + (es - (es / per) * per)) * H_C;
            }
            rowOff[m] = offv;
        }
    }
}

// ---------------------------------------------------------------------------
// MFMA bf16 GEMM, 64-row x 112-col blocks (blockIdx.y = column half).
// 4 waves, wave w owns rows [16w,16w+16) x NF fragments of this column half.
// ---------------------------------------------------------------------------
template<int NF, int ACT, bool SCATTER, bool OBF16>
__global__ __launch_bounds__(256) void mfma_gemm_k(
        const unsigned short* __restrict__ A, int lda,
        const unsigned short* __restrict__ Wt,
        const float* __restrict__ bias, void* __restrict__ Cv, int ldc,
        const int* __restrict__ rowOff, int M, int N, int Kp) {
    constexpr int BN = NF * 16;
    __shared__ unsigned short As[64][40];
    __shared__ unsigned short Bs[BN][40];
    const int tid  = threadIdx.x;
    const int bm   = blockIdx.x * 64;
    const int colBase = blockIdx.y * BN;
    const unsigned short* Wp = Wt + (size_t)colBase * Kp;
    const int w    = tid >> 6;
    const int lane = tid & 63;
    const int lr   = lane & 15;
    const int lk   = (lane >> 4) * 8;

    f32x4 acc[NF];
    #pragma unroll
    for (int nf = 0; nf < NF; ++nf) acc[nf] = (f32x4){0.f, 0.f, 0.f, 0.f};

    for (int k0 = 0; k0 < Kp; k0 += 32) {
        {   // stage A: 64 rows x 32 k = 256 uint4 chunks, 1 per thread
            int m = tid >> 2, c = tid & 3;
            int gm = bm + m;
            uint4 v = make_uint4(0u, 0u, 0u, 0u);
            if (gm < M) v = *reinterpret_cast<const uint4*>(A + (size_t)gm * lda + k0 + c * 8);
            *reinterpret_cast<uint4*>(&As[m][c * 8]) = v;
        }
        for (int i = tid; i < NF * 64; i += 256) {   // stage B
            int n = i >> 2, c = i & 3;
            uint4 v = *reinterpret_cast<const uint4*>(Wp + (size_t)n * Kp + k0 + c * 8);
            *reinterpret_cast<uint4*>(&Bs[n][c * 8]) = v;
        }
        __syncthreads();
        bf16x8 a = *reinterpret_cast<const bf16x8*>(&As[w * 16 + lr][lk]);
        #pragma unroll
        for (int nf = 0; nf < NF; ++nf) {
            bf16x8 b = *reinterpret_cast<const bf16x8*>(&Bs[nf * 16 + lr][lk]);
            acc[nf] = __builtin_amdgcn_mfma_f32_16x16x32_bf16(a, b, acc[nf], 0, 0, 0);
        }
        __syncthreads();
    }

    const int r0 = (lane >> 4) * 4;
    #pragma unroll
    for (int j = 0; j < 4; ++j) {
        int gm = bm + w * 16 + r0 + j;
        if (gm >= M) continue;
        size_t base;
        if (SCATTER && !OBF16) base = (size_t)rowOff[gm];
        else                   base = (size_t)gm * ldc;
        #pragma unroll
        for (int nf = 0; nf < NF; ++nf) {
            int gn = colBase + nf * 16 + lr;
            if (gn >= N) continue;
            float v = acc[nf][j];
            if (bias) v += bias[gn];
            if (ACT == 1) v = fmaxf(v, 0.f);
            if (ACT == 2) v = tanhf(v);
            if (OBF16) ((unsigned short*)Cv)[base + gn] = f2bf(v);
            else       ((float*)Cv)[base + gn] = v;
        }
    }
}

template<int NF, int ACT, bool SCATTER, bool OBF16>
static void launch_mfma(hipStream_t s, const unsigned short* A, int lda,
                        const unsigned short* Wt, const float* bias,
                        void* C, int ldc, const int* rowOff, int M, int N, int Kp,
                        int nsplit) {
    mfma_gemm_k<NF, ACT, SCATTER, OBF16><<<dim3((M + 63) / 64, nsplit), 256, 0, s>>>(
        A, lda, Wt, bias, C, ldc, rowOff, M, N, Kp);
}

// ---------------------------------------------------------------------------
// Small f32 GEMM (240-row rel transforms)
// ---------------------------------------------------------------------------
__global__ __launch_bounds__(256) void gemm_f32_k(
        const float* __restrict__ A, const float* __restrict__ W,
        float* __restrict__ C, int M, int N, int K) {
    constexpr int TS = 64, BK = 16;
    __shared__ float As[BK][TS];
    __shared__ float Bs[BK][TS];
    int bm = blockIdx.x * TS, bn = blockIdx.y * TS;
    int tid = threadIdx.x;
    int tx = tid & 15, ty = tid >> 4;
    float acc[4][4] = {};
    for (int k0 = 0; k0 < K; k0 += BK) {
        #pragma unroll
        for (int l = tid; l < TS * BK; l += 256) {
            int m = l >> 4, kk = l & 15;
            int gm = bm + m, gk = k0 + kk;
            As[kk][m] = (gm < M && gk < K) ? A[(size_t)gm * K + gk] : 0.f;
        }
        #pragma unroll
        for (int l = tid; l < TS * BK; l += 256) {
            int kk = l >> 6, n = l & 63;
            int gk = k0 + kk, gn = bn + n;
            Bs[kk][n] = (gk < K && gn < N) ? W[(size_t)gk * N + gn] : 0.f;
        }
        __syncthreads();
        #pragma unroll
        for (int kk = 0; kk < BK; ++kk) {
            float a[4], b[4];
            #pragma unroll
            for (int i = 0; i < 4; ++i) a[i] = As[kk][ty * 4 + i];
            #pragma unroll
            for (int j = 0; j < 4; ++j) b[j] = Bs[kk][tx * 4 + j];
            #pragma unroll
            for (int i = 0; i < 4; ++i)
                #pragma unroll
                for (int j = 0; j < 4; ++j) acc[i][j] += a[i] * b[j];
        }
        __syncthreads();
    }
    #pragma unroll
    for (int i = 0; i < 4; ++i) {
        int gm = bm + ty * 4 + i;
        if (gm >= M) continue;
        #pragma unroll
        for (int j = 0; j < 4; ++j) {
            int gn = bn + tx * 4 + j;
            if (gn < N) C[(size_t)gm * N + gn] = acc[i][j];
        }
    }
}

// ---------------------------------------------------------------------------
// Attention: one wave/row; bf16 QA + bf16 wh; wave-uniform mask skip
// ---------------------------------------------------------------------------
__global__ __launch_bounds__(256) void attn_k(
        const unsigned short* __restrict__ QAb, const unsigned short* __restrict__ whb,
        const int* __restrict__ ent_idx, const int* __restrict__ ent_mask,
        const int* __restrict__ rel_idx, const int* __restrict__ rel_mask,
        unsigned short* __restrict__ ctxOut, int N, int M) {
    int m = blockIdx.x * 4 + (threadIdx.x >> 6);
    int lane = threadIdx.x & 63;
    if (m >= M) return;
    const int* idxp;
    const int* mskp;
    if (m < N) { idxp = ent_idx + (size_t)m * MQ_C;        mskp = ent_mask + (size_t)m * MQ_C; }
    else       { idxp = rel_idx + (size_t)(m - N) * MQ_C;  mskp = rel_mask + (size_t)(m - N) * MQ_C; }

    int d0 = lane * 4;
    bool act = d0 < H_C;   // lanes 0..49
    float qa0 = 0.f, qa1 = 0.f, qa2 = 0.f, qa3 = 0.f;
    if (act) {
        uint2 u = *reinterpret_cast<const uint2*>(QAb + (size_t)m * H_C + d0);
        up2(u.x, qa0, qa1); up2(u.y, qa2, qa3);
    }
    int  idx[MQ_C];
    int  msk[MQ_C];
    float s[MQ_C];
    uint2 wr[MQ_C];
    #pragma unroll
    for (int k = 0; k < MQ_C; ++k) { idx[k] = idxp[k]; msk[k] = mskp[k]; }
    #pragma unroll
    for (int k = 0; k < MQ_C; ++k) {
        if (msk[k] != 0) {          // wave-uniform branch (one row per wave)
            float p = 0.f;
            if (act) {
                wr[k] = *reinterpret_cast<const uint2*>(whb + (size_t)idx[k] * H_C + d0);
                float e0, e1, e2, e3;
                up2(wr[k].x, e0, e1); up2(wr[k].y, e2, e3);
                p = qa0 * e0 + qa1 * e1 + qa2 * e2 + qa3 * e3;
            } else {
                wr[k] = make_uint2(0u, 0u);
            }
            #pragma unroll
            for (int off = 32; off; off >>= 1) p += __shfl_xor(p, off);
            s[k] = p;
        } else {
            s[k] = 0.f;             // masked score is exactly 0 (matches ref)
            wr[k] = make_uint2(0u, 0u);
        }
    }
    float mx = s[0];
    #pragma unroll
    for (int k = 1; k < MQ_C; ++k) mx = fmaxf(mx, s[k]);
    float den = 0.f;
    #pragma unroll
    for (int k = 0; k < MQ_C; ++k) { s[k] = expf(s[k] - mx); den += s[k]; }
    float inv = 1.f / den;
    if (act) {
        float c0 = 0.f, c1 = 0.f, c2 = 0.f, c3 = 0.f;
        #pragma unroll
        for (int k = 0; k < MQ_C; ++k) {
            if (msk[k] != 0) {      // masked keys contribute 0 to ctx
                float e0, e1, e2, e3;
                up2(wr[k].x, e0, e1); up2(wr[k].y, e2, e3);
                c0 += s[k] * e0; c1 += s[k] * e1; c2 += s[k] * e2; c3 += s[k] * e3;
            }
        }
        uint2 o;
        o.x = (unsigned)f2bf(c0 * inv) | ((unsigned)f2bf(c1 * inv) << 16);
        o.y = (unsigned)f2bf(c2 * inv) | ((unsigned)f2bf(c3 * inv) << 16);
        *reinterpret_cast<uint2*>(ctxOut + (size_t)m * 448 + d0) = o;
    }
}

// ---------------------------------------------------------------------------

static inline dim3 ew_grid(size_t total) {
    size_t b = (total + 255) / 256;
    if (b > 4096) b = 4096;
    return dim3((unsigned)b);
}

extern "C" void kernel_launch(void* const* d_in, const int* in_sizes, int n_in,
                              void* d_out, int out_size, void* d_ws, size_t ws_size,
                              hipStream_t stream) {
    const float* ent_embeds = (const float*)d_in[0];
    const float* rel_embeds = (const float*)d_in[1];
    const float* word_embeds= (const float*)d_in[2];
    const float* gcn_w1     = (const float*)d_in[3];
    const float* gcn_b1     = (const float*)d_in[4];
    const float* gcn_w2     = (const float*)d_in[5];
    const float* gcn_b2     = (const float*)d_in[6];
    const float* cg1_wn     = (const float*)d_in[7];
    const float* cg1_wl     = (const float*)d_in[8];
    const float* cg1_wr     = (const float*)d_in[9];
    const float* cg2_wn     = (const float*)d_in[10];
    const float* cg2_wl     = (const float*)d_in[11];
    const float* cg2_wr     = (const float*)d_in[12];
    const float* attn_wa    = (const float*)d_in[13];
    const float* attn_wc    = (const float*)d_in[14];
    const int* node_slot    = (const int*)d_in[15];
    const int* edge_src     = (const int*)d_in[16];
    const int* edge_dst     = (const int*)d_in[17];
    const int* edge_type    = (const int*)d_in[18];
    const int* word_id      = (const int*)d_in[19];
    const int* wsrc         = (const int*)d_in[20];
    const int* wdst         = (const int*)d_in[21];
    const int* ent_word_idx = (const int*)d_in[22];
    const int* ent_word_mask= (const int*)d_in[23];
    const int* rel_word_idx = (const int*)d_in[24];
    const int* rel_word_mask= (const int*)d_in[25];
    const int* r_ids_graph  = (const int*)d_in[26];
    const int* edge_slot    = (const int*)d_in[27];

    const int N    = in_sizes[15];          // 50000
    const int E    = in_sizes[16];          // 200000
    const int Nw   = in_sizes[19];          // 30000
    const int Ew   = in_sizes[20];          // 300000
    const int Rsel = in_sizes[27];          // 8192
    const int M    = N + Rsel;              // 58192
    const int divq = N / SEQ_C;
    const int per  = Rsel / NG_C;
    const int embBase = NG_C * SEQ_C * H_C;
    const size_t entElems  = (size_t)in_sizes[0];   // 2,000,000
    const size_t wembElems = (size_t)in_sizes[2];   // 4,000,000
    const int nNodes = Nw + N;              // 80000 combined CSR node space

    // ---- workspace carving (float-indexed, 16B-aligned sub-buffers)
    float* ws = (float*)d_ws;
    size_t o = 0;
    auto align4 = [&]() { o = (o + 3) & ~(size_t)3; };
    int* cdeg  = (int*)(ws + o); o += nNodes;
    int* coffs = (int*)(ws + o); o += nNodes;
    int* ccur  = (int*)(ws + o); o += nNodes;
    int* bktA  = (int*)(ws + o); o += Ew + E;
    int* bktB  = (int*)(ws + o); o += Ew + E;
    int* bsum  = (int*)(ws + o); o += 512;
    int* rowOff= (int*)(ws + o); o += M;
    float* rel1 = ws + o; o += (size_t)NREL_C * OUT_C;
    float* rel2 = ws + o; o += (size_t)NREL_C * H_C;
    align4();
    unsigned short* Wt      = (unsigned short*)(ws + o); o += 318976 / 2;
    align4();
    unsigned short* wh_bf   = (unsigned short*)(ws + o); o += ((size_t)Nw * H_C) / 2;
    align4();
    unsigned short* h1_bf   = (unsigned short*)(ws + o); o += ((size_t)N * OUT_C) / 2;
    align4();
    unsigned short* ent_bf  = (unsigned short*)(ws + o); o += entElems / 2;
    align4();
    unsigned short* wemb_bf = (unsigned short*)(ws + o); o += wembElems / 2;
    align4();
    unsigned short* AbfF    = (unsigned short*)(ws + o); o += ((size_t)M * 448) / 2;  // [ctx||Q||pad]
    align4();
    float* BIG = ws + o;    // phase-local
    unsigned short* wh1_bf = (unsigned short*)BIG;                                  // Nw*200
    unsigned short* AbfW   = (unsigned short*)(BIG + ((size_t)Nw * H_C) / 2);       // Nw*224
    unsigned short* AbfE   = (unsigned short*)BIG;                                  // N*448
    unsigned short* QAb    = (unsigned short*)d_out;                                // M*200 bf16

    // Wt segment bases (elements) — 224-row segments (except c1: 112)
    unsigned short* WT_g1 = Wt;                 // 224x128
    unsigned short* WT_g2 = Wt + 28672;         // 224x224
    unsigned short* WT_c1 = Wt + 78848;         // 112x416
    unsigned short* WT_c2 = Wt + 125440;        // 224x224
    unsigned short* WT_wa = Wt + 175616;        // 224x224
    unsigned short* WT_wc = Wt + 225792;        // 224x416

    // =============== prep + CSR build + weights ===============
    prep_k<<<ew_grid(entElems / 8 + wembElems / 8 + nNodes), 256, 0, stream>>>(
        ent_embeds, ent_bf, entElems / 8, word_embeds, wemb_bf, wembElems / 8,
        cdeg, nNodes);
    convw_all_k<<<ew_grid(318976), 256, 0, stream>>>(
        gcn_w1, gcn_w2, cg1_wn, cg1_wl, cg2_wn, cg2_wl, attn_wa, attn_wc, Wt);
    hist2_k<<<ew_grid((size_t)Ew + E), 256, 0, stream>>>(wdst, Ew, edge_dst, E, cdeg, Nw);
    {
        int nb = (nNodes + 255) / 256;     // 313 <= 512
        scanA_k<<<nb, 256, 0, stream>>>(cdeg, bsum, nNodes);
        scanB_k<<<1, 512, 0, stream>>>(bsum, nb);
        scanC_k<<<nb, 256, 0, stream>>>(cdeg, bsum, coffs, ccur, nNodes);
    }
    fill2_k<<<ew_grid((size_t)Ew + E), 256, 0, stream>>>(
        wdst, wsrc, word_id, Ew, edge_dst, edge_src, edge_type, E, ccur, Nw, bktA, bktB);
    // rel chains (f32, tiny)
    gemm_f32_k<<<dim3((NREL_C + 63) / 64, (OUT_C + 63) / 64), 256, 0, stream>>>(
        rel_embeds, cg1_wr, rel1, NREL_C, OUT_C, H_C);
    gemm_f32_k<<<dim3((NREL_C + 63) / 64, (H_C + 63) / 64), 256, 0, stream>>>(
        rel1, cg2_wr, rel2, NREL_C, H_C, OUT_C);
    post_k<<<ew_grid((size_t)Rsel * H_C + (size_t)M * 7), 256, 0, stream>>>(
        rel2, edge_type, r_ids_graph, AbfF, node_slot, edge_slot, rowOff,
        N, M, divq, per, embBase);

    // =============== phase W: word GCN ===============
    // L1: A = mean(wemb_bf[wid]) over wdst   [30000 x 128] (DUAL, K1=100)
    gather_mean_k<OUT_C, 0, 128, false, false, false, true><<<dim3((Nw + 3) / 4), 256, 0, stream>>>(
        wemb_bf, nullptr, nullptr, bktA, nullptr, coffs, cdeg, AbfW, Nw);
    launch_mfma<7, 1, false, true>(stream, AbfW, 128, WT_g1, gcn_b1, wh1_bf, H_C, nullptr, Nw, H_C, 128, 2);
    // L2: A = mean(wh1_bf[wsrc]) over wdst   [30000 x 224]
    gather_mean_k<H_C, 0, 224, false, false, false, false><<<dim3((Nw + 3) / 4), 256, 0, stream>>>(
        wh1_bf, nullptr, nullptr, bktB, nullptr, coffs, cdeg, AbfW, Nw);
    launch_mfma<7, 1, false, true>(stream, AbfW, 224, WT_g2, gcn_b2, wh_bf, H_C, nullptr, Nw, H_C, 224, 2);

    // =============== phase E: CompGCN ===============
    // L1: A = [mean(ent_bf[src%10k] - rel[type]) || ent_bf[n%10k]]   [50000 x 448]
    gather_mean_k<H_C, H_C, 448, true, true, true, false><<<dim3((N + 3) / 4), 256, 0, stream>>>(
        ent_bf, ent_bf, rel_embeds, bktA, bktB, coffs + Nw, cdeg + Nw, AbfE, N);
    launch_mfma<7, 1, false, true>(stream, AbfE, 448, WT_c1, nullptr, h1_bf, OUT_C, nullptr, N, OUT_C, 416, 1);
    // L2: A = [mean(h1_bf[src] - rel1[type]) || h1_bf[n]]   [50000 x 224] (DUAL, K1=100)
    gather_mean_k<OUT_C, OUT_C, 224, true, false, false, true><<<dim3((N + 3) / 4), 256, 0, stream>>>(
        h1_bf, h1_bf, rel1, bktA, bktB, coffs + Nw, cdeg + Nw, AbfE, N);
    // h2 -> bf16 directly into AbfF cols [200,400), rows [0,N)
    launch_mfma<7, 1, false, true>(stream, AbfE, 224, WT_c2, nullptr, AbfF + 200, 448, nullptr, N, H_C, 224, 2);

    // =============== phase A: attention + output ===============
    // QA = Q @ wa  (A = AbfF cols 200..424, lda=448) -> bf16 in d_out
    launch_mfma<7, 0, false, true>(stream, AbfF + 200, 448, WT_wa, nullptr, QAb, H_C, nullptr, M, H_C, 224, 2);
    attn_k<<<(M + 3) / 4, 256, 0, stream>>>(QAb, wh_bf, ent_word_idx, ent_word_mask,
                                            rel_word_idx, rel_word_mask, AbfF, N, M);
    // final: out = tanh([ctx||Q] @ wc) scattered into zeroed d_out
    hipMemsetAsync(d_out, 0, (size_t)out_size * 4, stream);
    launch_mfma<7, 2, true, false>(stream, AbfF, 448, WT_wc, nullptr, d_out, H_C, rowOff, M, H_C, 416, 2);
}